// Round 1
// baseline (11511.248 us; speedup 1.0000x reference)
//
#include <hip/hip_runtime.h>
#include <hip/hip_bf16.h>
#include <math.h>

typedef __hip_bfloat16 bf16;

#define HIDD   768
#define SEQL   197
#define NPATCH 196
#define PATCHD 256
#define NHEADS 12
#define NBATCH 8
#define OUTDIM 1000
#define NBLOCKS 6
#define EPSV   1e-5f

// ---------- helpers ----------
__device__ __forceinline__ float bf2f_raw(unsigned short u) {
  union { unsigned int i; float f; } w; w.i = ((unsigned int)u) << 16; return w.f;
}
template<typename T>
__device__ __forceinline__ float eltf(const T* p) {
  if constexpr (sizeof(T) == 4) return *p;
  else return __bfloat162float(*p);
}
template<typename T>
__device__ __forceinline__ void ld4v(const T* p, float v[4]) {
  if constexpr (sizeof(T) == 4) {
    float4 t = *reinterpret_cast<const float4*>(p);
    v[0] = t.x; v[1] = t.y; v[2] = t.z; v[3] = t.w;
  } else {
    ushort4 t = *reinterpret_cast<const ushort4*>(p);
    v[0] = bf2f_raw(t.x); v[1] = bf2f_raw(t.y); v[2] = bf2f_raw(t.z); v[3] = bf2f_raw(t.w);
  }
}
__device__ __forceinline__ void stc(float* p, float v) { *p = v; }
__device__ __forceinline__ void stc(bf16*  p, float v) { *p = __float2bfloat16(v); }

// ---------- generic tiled GEMM:  C = act(alpha * A @ op(B) + bias + resid) ----------
// A: [M,K] row-major (lda). BT=true: B is [N,K] (dot over K). BT=false: B is [K,N].
// z-batching: offsets = (z/zdiv)*s?z1 + (z%zdiv)*s?z2
template<int BM, int BN, bool BT, bool VECA, bool VECB, typename TA, typename TB, typename TC>
__global__ __launch_bounds__(256) void gemm_k(
    const TA* __restrict__ A, long long sAz1, long long sAz2, int lda,
    const TB* __restrict__ B, long long sBz1, long long sBz2, int ldb,
    TC* __restrict__ C, long long sCz1, long long sCz2, int ldc,
    const float* __restrict__ bias,
    const float* __restrict__ resid, long long sRz1, long long sRz2, int ldr,
    int zdiv, float alpha, int M, int N, int K, int act)
{
  constexpr int BK = 16;
  constexpr int TM = BM / 16;
  constexpr int TN = BN / 16;
  __shared__ float As[BK][BM];
  __shared__ float Bs[BK][BN];

  const int z  = blockIdx.z;
  const int z1 = z / zdiv, z2 = z % zdiv;
  A += z1 * sAz1 + z2 * sAz2;
  B += z1 * sBz1 + z2 * sBz2;
  C += z1 * sCz1 + z2 * sCz2;
  const float* R = resid ? (resid + z1 * sRz1 + z2 * sRz2) : nullptr;

  const int tid = threadIdx.x;
  const int tx = tid & 15, ty = tid >> 4;
  const int m0 = blockIdx.y * BM, n0 = blockIdx.x * BN;

  float acc[TM][TN];
#pragma unroll
  for (int i = 0; i < TM; ++i)
#pragma unroll
    for (int j = 0; j < TN; ++j) acc[i][j] = 0.f;

  for (int k0 = 0; k0 < K; k0 += BK) {
    // ---- stage A tile (transposed: As[k][m]) ----
    {
      constexpr int AV = (BM * BK / 4) / 256;
#pragma unroll
      for (int u = 0; u < AV; ++u) {
        const int vi = tid + u * 256;
        const int r  = vi / (BK / 4);
        const int c4 = (vi % (BK / 4)) * 4;
        const int gm = m0 + r, gk = k0 + c4;
        float v[4] = {0.f, 0.f, 0.f, 0.f};
        if constexpr (VECA) {
          if (gm < M) ld4v(A + (long long)gm * lda + gk, v);
        } else {
          if (gm < M) {
#pragma unroll
            for (int j = 0; j < 4; ++j)
              if (gk + j < K) v[j] = eltf(A + (long long)gm * lda + gk + j);
          }
        }
        As[c4 + 0][r] = v[0]; As[c4 + 1][r] = v[1];
        As[c4 + 2][r] = v[2]; As[c4 + 3][r] = v[3];
      }
    }
    // ---- stage B tile ----
    if constexpr (BT) {
      constexpr int BV = (BN * BK / 4) / 256;
#pragma unroll
      for (int u = 0; u < BV; ++u) {
        const int vi = tid + u * 256;
        const int r  = vi / (BK / 4);
        const int c4 = (vi % (BK / 4)) * 4;
        const int gn = n0 + r, gk = k0 + c4;
        float v[4] = {0.f, 0.f, 0.f, 0.f};
        if constexpr (VECB) {
          if (gn < N) ld4v(B + (long long)gn * ldb + gk, v);
        } else {
          if (gn < N) {
#pragma unroll
            for (int j = 0; j < 4; ++j)
              if (gk + j < K) v[j] = eltf(B + (long long)gn * ldb + gk + j);
          }
        }
        Bs[c4 + 0][r] = v[0]; Bs[c4 + 1][r] = v[1];
        Bs[c4 + 2][r] = v[2]; Bs[c4 + 3][r] = v[3];
      }
    } else {
      constexpr int BV = (BK * BN / 4) / 256;
#pragma unroll
      for (int u = 0; u < BV; ++u) {
        const int vi = tid + u * 256;
        const int kk = vi / (BN / 4);
        const int c4 = (vi % (BN / 4)) * 4;
        const int gk = k0 + kk, gn = n0 + c4;
        float v[4] = {0.f, 0.f, 0.f, 0.f};
        if (gk < K) {
          if constexpr (VECB) {
            if (gn + 3 < N) ld4v(B + (long long)gk * ldb + gn, v);
            else {
#pragma unroll
              for (int j = 0; j < 4; ++j)
                if (gn + j < N) v[j] = eltf(B + (long long)gk * ldb + gn + j);
            }
          } else {
#pragma unroll
            for (int j = 0; j < 4; ++j)
              if (gn + j < N) v[j] = eltf(B + (long long)gk * ldb + gn + j);
          }
        }
        Bs[kk][c4 + 0] = v[0]; Bs[kk][c4 + 1] = v[1];
        Bs[kk][c4 + 2] = v[2]; Bs[kk][c4 + 3] = v[3];
      }
    }
    __syncthreads();

#pragma unroll
    for (int kk = 0; kk < BK; ++kk) {
      float a[TM], bb[TN];
#pragma unroll
      for (int i = 0; i < TM; i += 4)
        *reinterpret_cast<float4*>(&a[i]) = *reinterpret_cast<const float4*>(&As[kk][ty * TM + i]);
#pragma unroll
      for (int j = 0; j < TN; j += 4)
        *reinterpret_cast<float4*>(&bb[j]) = *reinterpret_cast<const float4*>(&Bs[kk][tx * TN + j]);
#pragma unroll
      for (int i = 0; i < TM; ++i)
#pragma unroll
        for (int j = 0; j < TN; ++j) acc[i][j] = fmaf(a[i], bb[j], acc[i][j]);
    }
    __syncthreads();
  }

  // ---- epilogue ----
#pragma unroll
  for (int i = 0; i < TM; ++i) {
    const int gm = m0 + ty * TM + i;
    if (gm >= M) continue;
#pragma unroll
    for (int j = 0; j < TN; ++j) {
      const int gn = n0 + tx * TN + j;
      if (gn >= N) continue;
      float v = acc[i][j] * alpha;
      if (bias) v += bias[gn];
      if (R)    v += R[(long long)gm * ldr + gn];
      if (act)  v = tanhf(v);
      stc(C + (long long)gm * ldc + gn, v);
    }
  }
}

// ---------- LayerNorm over whole (SEQ,HID) per sample ----------
__global__ __launch_bounds__(256) void ln_part(const float* __restrict__ x, float* __restrict__ part) {
  const int b = blockIdx.x;            // 0..127
  const int n = b >> 4, seg = b & 15;
  const int per = (SEQL * HIDD / 4) / 16;   // 2364 float4s
  const float4* px = (const float4*)(x + (size_t)n * SEQL * HIDD);
  float s = 0.f, q = 0.f;
  for (int i = seg * per + threadIdx.x; i < (seg + 1) * per; i += 256) {
    float4 v = px[i];
    s += v.x + v.y + v.z + v.w;
    q += v.x * v.x + v.y * v.y + v.z * v.z + v.w * v.w;
  }
  for (int o = 32; o; o >>= 1) { s += __shfl_xor(s, o, 64); q += __shfl_xor(q, o, 64); }
  __shared__ float ls[8];
  const int wid = threadIdx.x >> 6, lane = threadIdx.x & 63;
  if (lane == 0) { ls[wid] = s; ls[4 + wid] = q; }
  __syncthreads();
  if (threadIdx.x == 0) {
    part[b] = ls[0] + ls[1] + ls[2] + ls[3];
    part[128 + b] = ls[4] + ls[5] + ls[6] + ls[7];
  }
}

__global__ void ln_fin(float* __restrict__ stats) {
  const int n = blockIdx.x; const int lane = threadIdx.x;  // 64 threads
  float s = (lane < 16) ? stats[n * 16 + lane] : 0.f;
  float q = (lane < 16) ? stats[128 + n * 16 + lane] : 0.f;
  for (int o = 8; o; o >>= 1) { s += __shfl_xor(s, o, 64); q += __shfl_xor(q, o, 64); }
  if (lane == 0) {
    const float inv = 1.f / (float)(SEQL * HIDD);
    const float m = s * inv;
    const float var = q * inv - m * m;
    stats[256 + 2 * n] = m;
    stats[257 + 2 * n] = rsqrtf(var + EPSV);
  }
}

__global__ __launch_bounds__(256) void ln_apply(const float* __restrict__ x,
    const float* __restrict__ g, const float* __restrict__ b,
    const float* __restrict__ st, float* __restrict__ y)
{
  const int tot = NBATCH * SEQL * HIDD / 4;
  for (int i = blockIdx.x * 256 + threadIdx.x; i < tot; i += gridDim.x * 256) {
    const int n  = i / (SEQL * HIDD / 4);
    const int se = i - n * (SEQL * HIDD / 4);
    const float m = st[2 * n], r = st[2 * n + 1];
    float4 xv = ((const float4*)x)[i];
    float4 gv = ((const float4*)g)[se];
    float4 bv = ((const float4*)b)[se];
    float4 o;
    o.x = (xv.x - m) * r * gv.x + bv.x;
    o.y = (xv.y - m) * r * gv.y + bv.y;
    o.z = (xv.z - m) * r * gv.z + bv.z;
    o.w = (xv.w - m) * r * gv.w + bv.w;
    ((float4*)y)[i] = o;
  }
}

// ---------- softmax over rows of length SEQ (one wave per row) ----------
__global__ __launch_bounds__(256) void softmax_rows(float* __restrict__ S, int nrows) {
  const long long row = (long long)blockIdx.x * 4 + (threadIdx.x >> 6);
  const int lane = threadIdx.x & 63;
  if (row >= nrows) return;
  float* p = S + row * SEQL;
  float v[4];
  float mx = -1e30f;
#pragma unroll
  for (int j = 0; j < 4; ++j) {
    const int t = lane + 64 * j;
    v[j] = (t < SEQL) ? p[t] : -1e30f;
    mx = fmaxf(mx, v[j]);
  }
  for (int o = 32; o; o >>= 1) mx = fmaxf(mx, __shfl_xor(mx, o, 64));
  float sum = 0.f;
#pragma unroll
  for (int j = 0; j < 4; ++j) {
    const int t = lane + 64 * j;
    v[j] = (t < SEQL) ? __expf(v[j] - mx) : 0.f;
    sum += v[j];
  }
  for (int o = 32; o; o >>= 1) sum += __shfl_xor(sum, o, 64);
  const float inv = 1.f / sum;
#pragma unroll
  for (int j = 0; j < 4; ++j) {
    const int t = lane + 64 * j;
    if (t < SEQL) p[t] = v[j] * inv;
  }
}

// ---------- CLS row init: Z[n,0,:] = cls + pos[0] ----------
__global__ void cls_pos(const float* __restrict__ cls, const float* __restrict__ pos,
                        float* __restrict__ Z) {
  const int n = blockIdx.x;
  for (int e = threadIdx.x; e < HIDD; e += 256)
    Z[(size_t)n * SEQL * HIDD + e] = cls[e] + pos[e];
}

// ---------------------------------------------------------------
extern "C" void kernel_launch(void* const* d_in, const int* in_sizes, int n_in,
                              void* d_out, int out_size, void* d_ws, size_t ws_size,
                              hipStream_t stream)
{
  const float* X    = (const float*)d_in[0];
  const float* Wp   = (const float*)d_in[1];
  const float* bp   = (const float*)d_in[2];
  const float* cls  = (const float*)d_in[3];
  const float* pos  = (const float*)d_in[4];
  const float* ln1g = (const float*)d_in[5];
  const float* ln1b = (const float*)d_in[6];
  const float* Wq   = (const float*)d_in[7];
  const float* bq   = (const float*)d_in[8];
  const float* Wk   = (const float*)d_in[9];
  const float* bk   = (const float*)d_in[10];
  const float* Wv   = (const float*)d_in[11];
  const float* bv   = (const float*)d_in[12];
  const float* Wo   = (const float*)d_in[13];
  const float* bo   = (const float*)d_in[14];
  const float* ln2g = (const float*)d_in[15];
  const float* ln2b = (const float*)d_in[16];
  const float* W2   = (const float*)d_in[17];
  const float* b2   = (const float*)d_in[18];
  const float* Wh   = (const float*)d_in[19];
  const float* bh   = (const float*)d_in[20];
  float* out = (float*)d_out;

  // workspace carve-up
  char* base = (char*)d_ws;
  size_t off = 0;
  auto alloc = [&](size_t bytes) -> char* {
    char* r = base + off;
    off += (bytes + 255) & ~(size_t)255;
    return r;
  };
  const size_t ZB = (size_t)NBATCH * SEQL * HIDD * 4;          // 4.84 MB
  const size_t SB = (size_t)NBATCH * NHEADS * SEQL * SEQL * 4; // 14.9 MB
  const size_t QB = (size_t)NBATCH * SEQL * NHEADS * HIDD * 2; // 29.0 MB (bf16)

  float* Z     = (float*)alloc(ZB);
  float* Xn    = (float*)alloc(ZB);    // reused as Ares (attn+Z) later in each block
  float* Y     = (float*)alloc(ZB);
  float* stats = (float*)alloc(4096);  // [0..127]=part sum, [128..255]=part sq, [256..271]=mean/rstd
  float* S     = (float*)alloc(SB);
  bf16*  Qb    = (bf16*)alloc(QB);
  bf16*  Kb    = (bf16*)alloc(QB);
  bf16*  Vb    = (bf16*)alloc(QB);
  bf16*  Hb    = (bf16*)alloc(QB);
  (void)ws_size; (void)in_sizes; (void)n_in; (void)out_size;

  const float scale = 1.0f / ((float)HIDD * (float)HIDD);
  const int HH = NHEADS * HIDD;            // 9216
  const int M_ALL = NBATCH * SEQL;         // 1576
  const long long sQn = (long long)SEQL * HH;  // per-n stride in Q/K/V/H
  const long long sSn = (long long)NHEADS * SEQL * SEQL;
  const long long sSh = (long long)SEQL * SEQL;

  // ---- embed: Z[n,0,:] = cls+pos[0]; Z[n,1+p,:] = X_patch @ Wp^T + bp + pos[1+p] ----
  cls_pos<<<dim3(NBATCH), 256, 0, stream>>>(cls, pos, Z);
  gemm_k<64, 64, true, true, true, float, float, float>
      <<<dim3(HIDD / 64, (NPATCH + 63) / 64, NBATCH), 256, 0, stream>>>(
      X, (long long)NPATCH * PATCHD, 0, PATCHD,
      Wp, 0, 0, PATCHD,
      Z + HIDD, (long long)SEQL * HIDD, 0, HIDD,
      bp, pos + HIDD, 0, 0, HIDD,
      1, 1.0f, NPATCH, HIDD, PATCHD, 0);

  for (int blk = 0; blk < NBLOCKS; ++blk) {
    // ---- LN1 ----
    ln_part<<<dim3(128), 256, 0, stream>>>(Z, stats);
    ln_fin<<<dim3(NBATCH), 64, 0, stream>>>(stats);
    ln_apply<<<dim3(1183), 256, 0, stream>>>(Z, ln1g, ln1b, stats + 256, Xn);

    // ---- QKV projections: [1576,768] @ [9216,768]^T -> bf16 [1576,9216] ----
    gemm_k<128, 128, true, true, true, float, float, bf16>
        <<<dim3(HH / 128, (M_ALL + 127) / 128, 1), 256, 0, stream>>>(
        Xn, 0, 0, HIDD, Wq, 0, 0, HIDD, Qb, 0, 0, HH,
        bq, nullptr, 0, 0, 0, 1, 1.0f, M_ALL, HH, HIDD, 0);
    gemm_k<128, 128, true, true, true, float, float, bf16>
        <<<dim3(HH / 128, (M_ALL + 127) / 128, 1), 256, 0, stream>>>(
        Xn, 0, 0, HIDD, Wk, 0, 0, HIDD, Kb, 0, 0, HH,
        bk, nullptr, 0, 0, 0, 1, 1.0f, M_ALL, HH, HIDD, 0);
    gemm_k<128, 128, true, true, true, float, float, bf16>
        <<<dim3(HH / 128, (M_ALL + 127) / 128, 1), 256, 0, stream>>>(
        Xn, 0, 0, HIDD, Wv, 0, 0, HIDD, Vb, 0, 0, HH,
        bv, nullptr, 0, 0, 0, 1, 1.0f, M_ALL, HH, HIDD, 0);

    // ---- scores: S[n,h] = scale * Q[n,h] @ K[n,h]^T  (z = n*12+h) ----
    gemm_k<64, 64, true, true, true, bf16, bf16, float>
        <<<dim3(4, 4, NBATCH * NHEADS), 256, 0, stream>>>(
        Qb, sQn, HIDD, HH,
        Kb, sQn, HIDD, HH,
        S, sSn, sSh, SEQL,
        nullptr, nullptr, 0, 0, 0,
        NHEADS, scale, SEQL, SEQL, HIDD, 0);

    // ---- softmax rows ----
    softmax_rows<<<dim3((NBATCH * NHEADS * SEQL + 3) / 4), 256, 0, stream>>>(
        S, NBATCH * NHEADS * SEQL);

    // ---- PV: H[n,h] = A[n,h] @ V[n,h]  (B not transposed) ----
    gemm_k<64, 64, false, false, true, float, bf16, bf16>
        <<<dim3(HIDD / 64, 4, NBATCH * NHEADS), 256, 0, stream>>>(
        S, sSn, sSh, SEQL,
        Vb, sQn, HIDD, HH,
        Hb, sQn, HIDD, HH,
        nullptr, nullptr, 0, 0, 0,
        NHEADS, 1.0f, SEQL, HIDD, SEQL, 0);

    // ---- Wo: Ares = H @ Wo^T + bo + Z  (into Xn buffer) ----
    gemm_k<64, 64, true, true, true, bf16, float, float>
        <<<dim3(HIDD / 64, (M_ALL + 63) / 64, 1), 256, 0, stream>>>(
        Hb, 0, 0, HH, Wo, 0, 0, HH, Xn, 0, 0, HIDD,
        bo, Z, 0, 0, HIDD, 1, 1.0f, M_ALL, HIDD, HH, 0);

    // ---- LN2 ----
    ln_part<<<dim3(128), 256, 0, stream>>>(Xn, stats);
    ln_fin<<<dim3(NBATCH), 64, 0, stream>>>(stats);
    ln_apply<<<dim3(1183), 256, 0, stream>>>(Xn, ln2g, ln2b, stats + 256, Y);

    // ---- W2: Z = Y @ W2^T + b2 ----
    gemm_k<64, 64, true, true, true, float, float, float>
        <<<dim3(HIDD / 64, (M_ALL + 63) / 64, 1), 256, 0, stream>>>(
        Y, 0, 0, HIDD, W2, 0, 0, HIDD, Z, 0, 0, HIDD,
        b2, nullptr, 0, 0, 0, 1, 1.0f, M_ALL, HIDD, HIDD, 0);
  }

  // ---- head: out = tanh(Z[:,0,:] @ Wh^T + bh) ----
  gemm_k<64, 64, true, true, true, float, float, float>
      <<<dim3((OUTDIM + 63) / 64, 1, 1), 256, 0, stream>>>(
      Z, 0, 0, SEQL * HIDD,
      Wh, 0, 0, HIDD,
      out, 0, 0, OUTDIM,
      bh, nullptr, 0, 0, 0,
      1, 1.0f, NBATCH, OUTDIM, HIDD, 1);
}

// Round 3
// 3351.775 us; speedup vs baseline: 3.4344x; 3.4344x over previous
//
#include <hip/hip_runtime.h>
#include <hip/hip_bf16.h>
#include <math.h>

typedef __hip_bfloat16 bf16;
typedef __attribute__((ext_vector_type(8))) short short8;
typedef __attribute__((ext_vector_type(4))) float f32x4;

#define HIDD   768
#define SEQL   197
#define NPATCH 196
#define PATCHD 256
#define NHEADS 12
#define NBATCH 8
#define OUTDIM 1000
#define NBLOCKS 6
#define EPSV   1e-5f
#define HH     (NHEADS * HIDD)       /* 9216 */
#define M_ALL  (NBATCH * SEQL)       /* 1576 */
#define SLD    224                   /* fp32 score row stride */
#define PLD    256                   /* bf16 prob row stride (zero-padded cols) */
#define KPV    224                   /* PV reduction length: 197 -> ceil32 = 224 */
#define KSPLIT 4

// ---------- helpers ----------
__device__ __forceinline__ unsigned short f2bf(float f) {
  union { bf16 h; unsigned short u; } cv; cv.h = __float2bfloat16(f); return cv.u;
}

// =================================================================
// MFMA GEMM.
//   BT=true : C = alpha * A @ B^T + bias ; B is [N,K] row-major (ldb).
//   BT=false: C = alpha * A @ B   + bias ; B is [K,N] row-major (ldb),
//             staged transposed into LDS (rows k >= Kvalid staged as zero).
//   A: bf16 [M,K] row-major (lda). B: bf16 or fp32 (fp32 converted in staging).
//   C: bf16 or fp32 (ldc). z-batching: elem offsets base + z1*s?z1 + z2*s?z2,
//   z1=z/zdiv, z2=z%zdiv. K multiple of 32. M/N edges zero-staged, store-masked.
// =================================================================
template<int BM, int BN, bool BT, bool BF16B, bool BF16C>
__global__ __launch_bounds__(256) void gemm_mfma(
    const unsigned short* __restrict__ A, long long sAz1, long long sAz2, int lda,
    const void* __restrict__ Bp, long long sBz1, long long sBz2, int ldb,
    void* __restrict__ Cp, long long sCz1, long long sCz2, int ldc,
    const float* __restrict__ bias, int zdiv, float alpha,
    int M, int N, int K, int Kvalid)
{
  constexpr int BK = 32;
  constexpr int LP = 40;   // padded LDS row stride (bf16 units)
  __shared__ unsigned short As[BM * LP];
  __shared__ unsigned short Bs[BN * LP];

  const int z  = blockIdx.z;
  const int z1 = z / zdiv, z2 = z - z1 * zdiv;
  const unsigned short* Ab = A + z1 * sAz1 + z2 * sAz2;
  const unsigned short* Bb = (const unsigned short*)Bp + z1 * sBz1 + z2 * sBz2;
  const float*          Bf = (const float*)Bp + z1 * sBz1 + z2 * sBz2;
  const long long coff = z1 * sCz1 + z2 * sCz2;

  const int tid = threadIdx.x;
  const int m0 = blockIdx.y * BM, n0 = blockIdx.x * BN;
  const int lane = tid & 63, wid = tid >> 6;
  const int wr = wid >> 1, wc = wid & 1;
  constexpr int WM = BM / 2, WN = BN / 2, TM = WM / 16, TN = WN / 16;
  const int lr = lane & 15, g = lane >> 4;
  const int srow = tid >> 2, scg = tid & 3;   // staging: row-in-64, 8-elem chunk

  f32x4 acc[TM][TN];
#pragma unroll
  for (int m = 0; m < TM; ++m)
#pragma unroll
    for (int n = 0; n < TN; ++n) acc[m][n] = (f32x4){0.f, 0.f, 0.f, 0.f};

  for (int k0 = 0; k0 < K; k0 += BK) {
    // ---- stage A (bf16, [M,K] -> As[m][k]) ----
#pragma unroll
    for (int u = 0; u < BM / 64; ++u) {
      const int row = u * 64 + srow;
      const int gm = m0 + row;
      int4 val = {0, 0, 0, 0};
      if (gm < M)
        val = *(const int4*)(Ab + (long long)gm * lda + k0 + scg * 8);
      *(int4*)&As[row * LP + scg * 8] = val;
    }
    // ---- stage B ----
    if constexpr (BT) {
      // B [N,K] row-major -> Bs[n][k]
#pragma unroll
      for (int u = 0; u < BN / 64; ++u) {
        const int row = u * 64 + srow;
        const int gn = n0 + row;
        int4 val = {0, 0, 0, 0};
        if (gn < N) {
          if constexpr (BF16B) {
            val = *(const int4*)(Bb + (long long)gn * ldb + k0 + scg * 8);
          } else {
            const float* p = Bf + (long long)gn * ldb + k0 + scg * 8;
            float4 f0 = ((const float4*)p)[0];
            float4 f1 = ((const float4*)p)[1];
            unsigned short t[8] = { f2bf(f0.x), f2bf(f0.y), f2bf(f0.z), f2bf(f0.w),
                                    f2bf(f1.x), f2bf(f1.y), f2bf(f1.z), f2bf(f1.w) };
            val = *(int4*)t;
          }
        }
        *(int4*)&Bs[row * LP + scg * 8] = val;
      }
    } else {
      // B [K,N] row-major -> transpose-stage into Bs[n][k].
      // Thread handles a (k-pair, n-octet): 8 contiguous n from rows gk0,gk0+1.
      constexpr int CH = BN / 8;        // n-octets per k-row
      constexpr int KP = BK / 2;        // 16 k-pairs
      static_assert(KP * CH <= 256, "staging exceeds block");
      if (tid < KP * CH) {
        const int kp = tid / CH;
        const int c8 = (tid - kp * CH) * 8;
        const int gn = n0 + c8;
        const int gk0 = k0 + 2 * kp;
        unsigned short r0[8] = {0,0,0,0,0,0,0,0};
        unsigned short r1[8] = {0,0,0,0,0,0,0,0};
        if constexpr (BF16B) {
          if (gk0 < Kvalid) {
            if (gn + 7 < N) *(int4*)r0 = *(const int4*)(Bb + (long long)gk0 * ldb + gn);
            else { for (int j = 0; j < 8; ++j) if (gn + j < N) r0[j] = Bb[(long long)gk0 * ldb + gn + j]; }
          }
          if (gk0 + 1 < Kvalid) {
            if (gn + 7 < N) *(int4*)r1 = *(const int4*)(Bb + (long long)(gk0 + 1) * ldb + gn);
            else { for (int j = 0; j < 8; ++j) if (gn + j < N) r1[j] = Bb[(long long)(gk0 + 1) * ldb + gn + j]; }
          }
        } else {
          if (gk0 < Kvalid) { for (int j = 0; j < 8; ++j) if (gn + j < N) r0[j] = f2bf(Bf[(long long)gk0 * ldb + gn + j]); }
          if (gk0 + 1 < Kvalid) { for (int j = 0; j < 8; ++j) if (gn + j < N) r1[j] = f2bf(Bf[(long long)(gk0 + 1) * ldb + gn + j]); }
        }
#pragma unroll
        for (int j = 0; j < 8; ++j)
          *(unsigned int*)&Bs[(c8 + j) * LP + 2 * kp] =
              (unsigned int)r0[j] | ((unsigned int)r1[j] << 16);
      }
    }
    __syncthreads();

    // ---- fragments + MFMA ----
    short8 a[TM], b[TN];
#pragma unroll
    for (int m = 0; m < TM; ++m)
      a[m] = *(const short8*)&As[(wr * WM + m * 16 + lr) * LP + g * 8];
#pragma unroll
    for (int n = 0; n < TN; ++n)
      b[n] = *(const short8*)&Bs[(wc * WN + n * 16 + lr) * LP + g * 8];
#pragma unroll
    for (int m = 0; m < TM; ++m)
#pragma unroll
      for (int n = 0; n < TN; ++n)
        acc[m][n] = __builtin_amdgcn_mfma_f32_16x16x32_bf16(a[m], b[n], acc[m][n], 0, 0, 0);
    __syncthreads();
  }

  // ---- epilogue: D col = lane&15, row = (lane>>4)*4 + r  [m89-verified] ----
#pragma unroll
  for (int m = 0; m < TM; ++m) {
#pragma unroll
    for (int n = 0; n < TN; ++n) {
      const int gn = n0 + wc * WN + n * 16 + lr;
      if (gn >= N) continue;
      const float bv = bias ? bias[gn] : 0.f;
#pragma unroll
      for (int r = 0; r < 4; ++r) {
        const int gm = m0 + wr * WM + m * 16 + g * 4 + r;
        if (gm >= M) continue;
        const float v = acc[m][n][r] * alpha + bv;
        if constexpr (BF16C)
          ((unsigned short*)Cp)[coff + (long long)gm * ldc + gn] = f2bf(v);
        else
          ((float*)Cp)[coff + (long long)gm * ldc + gn] = v;
      }
    }
  }
}

// =================================================================
// fp32 vector-ALU GEMM (tiny patch-embed and head)
// =================================================================
template<int BM, int BN>
__global__ __launch_bounds__(256) void gemm_k(
    const float* __restrict__ A, long long sAz1, int lda,
    const float* __restrict__ B, int ldb,
    float* __restrict__ C, long long sCz1, int ldc,
    const float* __restrict__ bias,
    const float* __restrict__ resid, int ldr,
    float alpha, int M, int N, int K, int act)
{
  constexpr int BK = 16;
  constexpr int TM = BM / 16;
  constexpr int TN = BN / 16;
  __shared__ float As[BK][BM];
  __shared__ float Bs[BK][BN];

  const int z = blockIdx.z;
  A += z * sAz1;
  C += z * sCz1;
  const float* R = resid;

  const int tid = threadIdx.x;
  const int tx = tid & 15, ty = tid >> 4;
  const int m0 = blockIdx.y * BM, n0 = blockIdx.x * BN;

  float acc[TM][TN];
#pragma unroll
  for (int i = 0; i < TM; ++i)
#pragma unroll
    for (int j = 0; j < TN; ++j) acc[i][j] = 0.f;

  for (int k0 = 0; k0 < K; k0 += BK) {
    {
      constexpr int AV = (BM * BK / 4) / 256;
#pragma unroll
      for (int u = 0; u < AV; ++u) {
        const int vi = tid + u * 256;
        const int r  = vi / (BK / 4);
        const int c4 = (vi % (BK / 4)) * 4;
        const int gm = m0 + r, gk = k0 + c4;
        float4 v = {0.f, 0.f, 0.f, 0.f};
        if (gm < M) v = *(const float4*)(A + (long long)gm * lda + gk);
        As[c4 + 0][r] = v.x; As[c4 + 1][r] = v.y;
        As[c4 + 2][r] = v.z; As[c4 + 3][r] = v.w;
      }
    }
    {
      constexpr int BV = (BN * BK / 4) / 256;
#pragma unroll
      for (int u = 0; u < BV; ++u) {
        const int vi = tid + u * 256;
        const int r  = vi / (BK / 4);
        const int c4 = (vi % (BK / 4)) * 4;
        const int gn = n0 + r, gk = k0 + c4;
        float4 v = {0.f, 0.f, 0.f, 0.f};
        if (gn < N) v = *(const float4*)(B + (long long)gn * ldb + gk);
        Bs[c4 + 0][r] = v.x; Bs[c4 + 1][r] = v.y;
        Bs[c4 + 2][r] = v.z; Bs[c4 + 3][r] = v.w;
      }
    }
    __syncthreads();
#pragma unroll
    for (int kk = 0; kk < BK; ++kk) {
      float a[TM], bb[TN];
#pragma unroll
      for (int i = 0; i < TM; i += 4)
        *reinterpret_cast<float4*>(&a[i]) = *reinterpret_cast<const float4*>(&As[kk][ty * TM + i]);
#pragma unroll
      for (int j = 0; j < TN; j += 4)
        *reinterpret_cast<float4*>(&bb[j]) = *reinterpret_cast<const float4*>(&Bs[kk][tx * TN + j]);
#pragma unroll
      for (int i = 0; i < TM; ++i)
#pragma unroll
        for (int j = 0; j < TN; ++j) acc[i][j] = fmaf(a[i], bb[j], acc[i][j]);
    }
    __syncthreads();
  }

#pragma unroll
  for (int i = 0; i < TM; ++i) {
    const int gm = m0 + ty * TM + i;
    if (gm >= M) continue;
#pragma unroll
    for (int j = 0; j < TN; ++j) {
      const int gn = n0 + tx * TN + j;
      if (gn >= N) continue;
      float v = acc[i][j] * alpha;
      if (bias) v += bias[gn];
      if (R)    v += R[(long long)gm * ldr + gn];
      if (act)  v = tanhf(v);
      C[(long long)gm * ldc + gn] = v;
    }
  }
}

// ---------- LayerNorm over whole (SEQ,HID) per sample ----------
__global__ __launch_bounds__(256) void ln_part(const float* __restrict__ x, float* __restrict__ part) {
  const int b = blockIdx.x;            // 0..127
  const int n = b >> 4, seg = b & 15;
  const int per = (SEQL * HIDD / 4) / 16;
  const float4* px = (const float4*)(x + (size_t)n * SEQL * HIDD);
  float s = 0.f, q = 0.f;
  for (int i = seg * per + threadIdx.x; i < (seg + 1) * per; i += 256) {
    float4 v = px[i];
    s += v.x + v.y + v.z + v.w;
    q += v.x * v.x + v.y * v.y + v.z * v.z + v.w * v.w;
  }
  for (int o = 32; o; o >>= 1) { s += __shfl_xor(s, o, 64); q += __shfl_xor(q, o, 64); }
  __shared__ float ls[8];
  const int wid = threadIdx.x >> 6, lane = threadIdx.x & 63;
  if (lane == 0) { ls[wid] = s; ls[4 + wid] = q; }
  __syncthreads();
  if (threadIdx.x == 0) {
    part[b] = ls[0] + ls[1] + ls[2] + ls[3];
    part[128 + b] = ls[4] + ls[5] + ls[6] + ls[7];
  }
}

__global__ void ln_fin(float* __restrict__ stats) {
  const int n = blockIdx.x; const int lane = threadIdx.x;  // 64 threads
  float s = (lane < 16) ? stats[n * 16 + lane] : 0.f;
  float q = (lane < 16) ? stats[128 + n * 16 + lane] : 0.f;
  for (int o = 8; o; o >>= 1) { s += __shfl_xor(s, o, 64); q += __shfl_xor(q, o, 64); }
  if (lane == 0) {
    const float inv = 1.f / (float)(SEQL * HIDD);
    const float m = s * inv;
    const float var = q * inv - m * m;
    stats[256 + 2 * n] = m;
    stats[257 + 2 * n] = rsqrtf(var + EPSV);
  }
}

// LN apply -> bf16 output
__global__ __launch_bounds__(256) void ln_apply_bf(const float* __restrict__ x,
    const float* __restrict__ g, const float* __restrict__ b,
    const float* __restrict__ st, unsigned short* __restrict__ y)
{
  const int tot = NBATCH * SEQL * HIDD / 4;
  for (int i = blockIdx.x * 256 + threadIdx.x; i < tot; i += gridDim.x * 256) {
    const int n  = i / (SEQL * HIDD / 4);
    const int se = i - n * (SEQL * HIDD / 4);
    const float m = st[2 * n], r = st[2 * n + 1];
    float4 xv = ((const float4*)x)[i];
    float4 gv = ((const float4*)g)[se];
    float4 bv = ((const float4*)b)[se];
    ushort4 o;
    o.x = f2bf((xv.x - m) * r * gv.x + bv.x);
    o.y = f2bf((xv.y - m) * r * gv.y + bv.y);
    o.z = f2bf((xv.z - m) * r * gv.z + bv.z);
    o.w = f2bf((xv.w - m) * r * gv.w + bv.w);
    ((ushort4*)y)[i] = o;
  }
}

// ---------- softmax fp32 in (ld 224) -> bf16 out (ld 256, zero-padded) ----------
__global__ __launch_bounds__(256) void softmax_bf(const float* __restrict__ S,
                                                  unsigned short* __restrict__ P, int nrows) {
  const int row = blockIdx.x * 4 + (threadIdx.x >> 6);
  const int lane = threadIdx.x & 63;
  if (row >= nrows) return;
  const float* p = S + (long long)row * SLD;
  float v[4];
  float mx = -1e30f;
#pragma unroll
  for (int j = 0; j < 4; ++j) {
    const int t = lane + 64 * j;
    v[j] = (t < SEQL) ? p[t] : -1e30f;
    mx = fmaxf(mx, v[j]);
  }
  for (int o = 32; o; o >>= 1) mx = fmaxf(mx, __shfl_xor(mx, o, 64));
  float sum = 0.f;
#pragma unroll
  for (int j = 0; j < 4; ++j) {
    const int t = lane + 64 * j;
    v[j] = (t < SEQL) ? __expf(v[j] - mx) : 0.f;
    sum += v[j];
  }
  for (int o = 32; o; o >>= 1) sum += __shfl_xor(sum, o, 64);
  const float inv = 1.f / sum;
  unsigned short* q = P + (long long)row * PLD;
#pragma unroll
  for (int j = 0; j < 4; ++j) {
    const int t = lane + 64 * j;
    q[t] = f2bf(v[j] * inv);   // pad cols (>=SEQL) get 0
  }
}

// ---------- Wo split-K reduce: Ares = sum_s Cpart[s] + bo + Z ----------
__global__ __launch_bounds__(256) void wo_reduce(const float4* __restrict__ Cp,
    const float4* __restrict__ Z4, const float4* __restrict__ bo4,
    float4* __restrict__ out4)
{
  const int tot = M_ALL * HIDD / 4;    // 302592
  for (int i = blockIdx.x * 256 + threadIdx.x; i < tot; i += gridDim.x * 256) {
    float4 a = Cp[i], b = Cp[tot + i], c = Cp[2 * tot + i], d = Cp[3 * tot + i];
    float4 z = Z4[i];
    float4 bb = bo4[i % (HIDD / 4)];
    float4 o;
    o.x = a.x + b.x + c.x + d.x + z.x + bb.x;
    o.y = a.y + b.y + c.y + d.y + z.y + bb.y;
    o.z = a.z + b.z + c.z + d.z + z.z + bb.z;
    o.w = a.w + b.w + c.w + d.w + z.w + bb.w;
    out4[i] = o;
  }
}

// ---------- CLS row init ----------
__global__ void cls_pos(const float* __restrict__ cls, const float* __restrict__ pos,
                        float* __restrict__ Z) {
  const int n = blockIdx.x;
  for (int e = threadIdx.x; e < HIDD; e += 256)
    Z[(size_t)n * SEQL * HIDD + e] = cls[e] + pos[e];
}

// ---------------------------------------------------------------
extern "C" void kernel_launch(void* const* d_in, const int* in_sizes, int n_in,
                              void* d_out, int out_size, void* d_ws, size_t ws_size,
                              hipStream_t stream)
{
  const float* X    = (const float*)d_in[0];
  const float* Wp   = (const float*)d_in[1];
  const float* bp   = (const float*)d_in[2];
  const float* cls  = (const float*)d_in[3];
  const float* pos  = (const float*)d_in[4];
  const float* ln1g = (const float*)d_in[5];
  const float* ln1b = (const float*)d_in[6];
  const float* Wq   = (const float*)d_in[7];
  const float* bq   = (const float*)d_in[8];
  const float* Wk   = (const float*)d_in[9];
  const float* bk   = (const float*)d_in[10];
  const float* Wv   = (const float*)d_in[11];
  const float* bv   = (const float*)d_in[12];
  const float* Wo   = (const float*)d_in[13];
  const float* bo   = (const float*)d_in[14];
  const float* ln2g = (const float*)d_in[15];
  const float* ln2b = (const float*)d_in[16];
  const float* W2   = (const float*)d_in[17];
  const float* b2   = (const float*)d_in[18];
  const float* Wh   = (const float*)d_in[19];
  const float* bh   = (const float*)d_in[20];
  float* out = (float*)d_out;
  (void)in_sizes; (void)n_in; (void)out_size; (void)ws_size;

  // workspace carve-up (~126 MB; round 1 proved >=146 MB usable)
  char* base = (char*)d_ws;
  size_t off = 0;
  auto alloc = [&](size_t bytes) -> char* {
    char* r = base + off;
    off += (bytes + 255) & ~(size_t)255;
    return r;
  };
  const size_t ZB  = (size_t)M_ALL * HIDD * 4;
  const size_t XB  = (size_t)M_ALL * HIDD * 2;
  const size_t SFB = (size_t)NBATCH * NHEADS * SEQL * SLD * 4;
  const size_t PB  = (size_t)NBATCH * NHEADS * SEQL * PLD * 2;
  const size_t QB  = (size_t)M_ALL * HH * 2;

  float*          Z     = (float*)alloc(ZB);
  float*          Ares  = (float*)alloc(ZB);
  unsigned short* Xnb   = (unsigned short*)alloc(XB);   // LN output (bf16)
  float*          stats = (float*)alloc(4096);
  float*          Sf    = (float*)alloc(SFB);
  unsigned short* Pb    = (unsigned short*)alloc(PB);
  unsigned short* Qb    = (unsigned short*)alloc(QB);
  unsigned short* Kb    = (unsigned short*)alloc(QB);
  unsigned short* Vb    = (unsigned short*)alloc(QB);
  unsigned short* Hb    = Qb;                           // PV out (Q dead after scores)
  float*          Cpart = (float*)Kb;                   // 19.4 MB <= 29 MB (K dead after scores)

  const float scale = 1.0f / ((float)HIDD * (float)HIDD);
  const long long sQn = (long long)SEQL * HH;
  const long long sSn = (long long)NHEADS * SEQL * SLD;
  const long long sSh = (long long)SEQL * SLD;
  const long long sPn = (long long)NHEADS * SEQL * PLD;
  const long long sPh = (long long)SEQL * PLD;

  // ---- embed ----
  cls_pos<<<dim3(NBATCH), 256, 0, stream>>>(cls, pos, Z);
  gemm_k<64, 64><<<dim3(HIDD / 64, (NPATCH + 63) / 64, NBATCH), 256, 0, stream>>>(
      X, (long long)NPATCH * PATCHD, PATCHD,
      Wp, PATCHD,
      Z + HIDD, (long long)SEQL * HIDD, HIDD,
      bp, pos + HIDD, HIDD,
      1.0f, NPATCH, HIDD, PATCHD, 0);

  for (int blk = 0; blk < NBLOCKS; ++blk) {
    // ---- LN1 -> Xnb (bf16) ----
    ln_part<<<dim3(128), 256, 0, stream>>>(Z, stats);
    ln_fin<<<dim3(NBATCH), 64, 0, stream>>>(stats);
    ln_apply_bf<<<dim3(1182), 256, 0, stream>>>(Z, ln1g, ln1b, stats + 256, Xnb);

    // ---- QKV: [1576,768]bf16 @ [9216,768]fp32^T -> bf16 ----
    gemm_mfma<128, 128, true, false, true><<<dim3(HH / 128, 13, 1), 256, 0, stream>>>(
        Xnb, 0, 0, HIDD, Wq, 0, 0, HIDD, Qb, 0, 0, HH,
        bq, 1, 1.0f, M_ALL, HH, HIDD, HIDD);
    gemm_mfma<128, 128, true, false, true><<<dim3(HH / 128, 13, 1), 256, 0, stream>>>(
        Xnb, 0, 0, HIDD, Wk, 0, 0, HIDD, Kb, 0, 0, HH,
        bk, 1, 1.0f, M_ALL, HH, HIDD, HIDD);
    gemm_mfma<128, 128, true, false, true><<<dim3(HH / 128, 13, 1), 256, 0, stream>>>(
        Xnb, 0, 0, HIDD, Wv, 0, 0, HIDD, Vb, 0, 0, HH,
        bv, 1, 1.0f, M_ALL, HH, HIDD, HIDD);

    // ---- scores: Sf[z] = scale * Q[z] @ K[z]^T  (z = n*12+h) ----
    gemm_mfma<64, 64, true, true, false><<<dim3(4, 4, NBATCH * NHEADS), 256, 0, stream>>>(
        Qb, sQn, HIDD, HH,
        Kb, sQn, HIDD, HH,
        Sf, sSn, sSh, SLD,
        nullptr, NHEADS, scale, SEQL, SEQL, HIDD, HIDD);

    // ---- softmax rows -> Pb (bf16, cols padded to 256 with zeros) ----
    softmax_bf<<<dim3(NBATCH * NHEADS * SEQL / 4), 256, 0, stream>>>(
        Sf, Pb, NBATCH * NHEADS * SEQL);

    // ---- PV: H[z] = P[z] @ V[z]  (BT=false: B is [K,N]; K=224, V rows valid<197) ----
    gemm_mfma<64, 128, false, true, true><<<dim3(HIDD / 128, 4, NBATCH * NHEADS), 256, 0, stream>>>(
        Pb, sPn, sPh, PLD,
        Vb, sQn, HIDD, HH,
        Hb, sQn, HIDD, HH,
        nullptr, NHEADS, 1.0f, SEQL, HIDD, KPV, SEQL);

    // ---- Wo split-K: Cpart[s] = H[:, s*2304:(s+1)*2304] @ Wo_s^T ----
    gemm_mfma<128, 128, true, false, false><<<dim3(HIDD / 128, 13, KSPLIT), 256, 0, stream>>>(
        Hb, 0, HH / KSPLIT, HH,
        Wo, 0, HH / KSPLIT, HH,
        Cpart, 0, (long long)M_ALL * HIDD, HIDD,
        nullptr, KSPLIT, 1.0f, M_ALL, HIDD, HH / KSPLIT, HH / KSPLIT);

    // ---- reduce + bias + residual -> Ares ----
    wo_reduce<<<dim3(1182), 256, 0, stream>>>(
        (const float4*)Cpart, (const float4*)Z, (const float4*)bo, (float4*)Ares);

    // ---- LN2 -> Xnb (bf16) ----
    ln_part<<<dim3(128), 256, 0, stream>>>(Ares, stats);
    ln_fin<<<dim3(NBATCH), 64, 0, stream>>>(stats);
    ln_apply_bf<<<dim3(1182), 256, 0, stream>>>(Ares, ln2g, ln2b, stats + 256, Xnb);

    // ---- W2: Z = Xnb @ W2^T + b2 (fp32 out) ----
    gemm_mfma<128, 64, true, false, false><<<dim3(HIDD / 64, 13, 1), 256, 0, stream>>>(
        Xnb, 0, 0, HIDD, W2, 0, 0, HIDD, Z, 0, 0, HIDD,
        b2, 1, 1.0f, M_ALL, HIDD, HIDD, HIDD);
  }

  // ---- head: out = tanh(Z[:,0,:] @ Wh^T + bh) ----
  gemm_k<64, 64><<<dim3((OUTDIM + 63) / 64, 1, 1), 256, 0, stream>>>(
      Z, 0, SEQL * HIDD,
      Wh, HIDD,
      out, 0, OUTDIM,
      bh, nullptr, 0,
      1.0f, NBATCH, OUTDIM, HIDD, 1);
}

// Round 4
// 2631.258 us; speedup vs baseline: 4.3748x; 1.2738x over previous
//
#include <hip/hip_runtime.h>
#include <hip/hip_bf16.h>
#include <math.h>

typedef __hip_bfloat16 bf16;
typedef __attribute__((ext_vector_type(8))) short short8;
typedef __attribute__((ext_vector_type(4))) float f32x4;

#define HIDD   768
#define SEQL   197
#define NPATCH 196
#define PATCHD 256
#define NHEADS 12
#define NBATCH 8
#define OUTDIM 1000
#define NBLOCKS 6
#define EPSV   1e-5f
#define HH     (NHEADS * HIDD)       /* 9216 */
#define HH3    (3 * HH)              /* 27648 */
#define M_ALL  (NBATCH * SEQL)       /* 1576 */
#define SLD    224                   /* fp32 score row stride */
#define PLD    256                   /* bf16 prob row stride (zero-padded cols) */
#define KPV    224                   /* PV reduction length: 197 -> ceil32 */
#define KSPLIT 4

// ---------- helpers ----------
__device__ __forceinline__ unsigned short f2bf(float f) {
  union { bf16 h; unsigned short u; } cv; cv.h = __float2bfloat16(f); return cv.u;
}

// ---------- fp32 -> bf16 convert (n multiple of 4) ----------
__global__ __launch_bounds__(256) void cvt_bf(const float4* __restrict__ src,
                                              ushort4* __restrict__ dst, int n4) {
  for (int i = blockIdx.x * 256 + threadIdx.x; i < n4; i += gridDim.x * 256) {
    float4 v = src[i];
    ushort4 o;
    o.x = f2bf(v.x); o.y = f2bf(v.y); o.z = f2bf(v.z); o.w = f2bf(v.w);
    dst[i] = o;
  }
}

// =================================================================
// MFMA GEMM (bf16 A and B, fp32 accum).
//   BT=true : C = alpha * A @ B^T + bias ; B is [N,K] row-major (ldb).
//   BT=false: C = alpha * A @ B   + bias ; B is [K,N] row-major (ldb),
//             transpose-staged (rows k >= Kvalid staged as zero).
//   C: bf16 or fp32 (ldc). z-batching: elem offsets base + z1*s?z1 + z2*s?z2,
//   z1=z/zdiv, z2=z%zdiv. K multiple of 32. M/N edges zero-staged, store-masked.
// =================================================================
template<int BM, int BN, bool BT, bool BF16C>
__global__ __launch_bounds__(256) void gemm_mfma(
    const unsigned short* __restrict__ A, long long sAz1, long long sAz2, int lda,
    const unsigned short* __restrict__ Bb, long long sBz1, long long sBz2, int ldb,
    void* __restrict__ Cp, long long sCz1, long long sCz2, int ldc,
    const float* __restrict__ bias, int zdiv, float alpha,
    int M, int N, int K, int Kvalid)
{
  constexpr int BK = 32;
  constexpr int LP = 40;   // padded LDS row stride (bf16 units)
  __shared__ unsigned short As[BM * LP];
  __shared__ unsigned short Bs[BN * LP];

  const int z  = blockIdx.z;
  const int z1 = z / zdiv, z2 = z - z1 * zdiv;
  const unsigned short* Ab = A + z1 * sAz1 + z2 * sAz2;
  const unsigned short* Bp = Bb + z1 * sBz1 + z2 * sBz2;
  const long long coff = z1 * sCz1 + z2 * sCz2;

  const int tid = threadIdx.x;
  const int m0 = blockIdx.y * BM, n0 = blockIdx.x * BN;
  const int lane = tid & 63, wid = tid >> 6;
  const int wr = wid >> 1, wc = wid & 1;
  constexpr int WM = BM / 2, WN = BN / 2, TM = WM / 16, TN = WN / 16;
  const int lr = lane & 15, g = lane >> 4;
  const int srow = tid >> 2, scg = tid & 3;   // staging: row-in-64, 8-elem chunk

  f32x4 acc[TM][TN];
#pragma unroll
  for (int m = 0; m < TM; ++m)
#pragma unroll
    for (int n = 0; n < TN; ++n) acc[m][n] = (f32x4){0.f, 0.f, 0.f, 0.f};

  for (int k0 = 0; k0 < K; k0 += BK) {
    // ---- stage A (bf16, [M,K] -> As[m][k]) ----
#pragma unroll
    for (int u = 0; u < BM / 64; ++u) {
      const int row = u * 64 + srow;
      const int gm = m0 + row;
      int4 val = {0, 0, 0, 0};
      if (gm < M)
        val = *(const int4*)(Ab + (long long)gm * lda + k0 + scg * 8);
      *(int4*)&As[row * LP + scg * 8] = val;
    }
    // ---- stage B ----
    if constexpr (BT) {
      // B [N,K] row-major -> Bs[n][k]
#pragma unroll
      for (int u = 0; u < BN / 64; ++u) {
        const int row = u * 64 + srow;
        const int gn = n0 + row;
        int4 val = {0, 0, 0, 0};
        if (gn < N)
          val = *(const int4*)(Bp + (long long)gn * ldb + k0 + scg * 8);
        *(int4*)&Bs[row * LP + scg * 8] = val;
      }
    } else {
      // B [K,N] row-major -> transpose-stage into Bs[n][k]
      constexpr int CH = BN / 8;        // n-octets per k-row
      constexpr int KP = BK / 2;        // 16 k-pairs
      static_assert(KP * CH <= 256, "staging exceeds block");
      if (tid < KP * CH) {
        const int kp = tid / CH;
        const int c8 = (tid - kp * CH) * 8;
        const int gn = n0 + c8;
        const int gk0 = k0 + 2 * kp;
        unsigned short r0[8] = {0,0,0,0,0,0,0,0};
        unsigned short r1[8] = {0,0,0,0,0,0,0,0};
        if (gk0 < Kvalid) {
          if (gn + 7 < N) *(int4*)r0 = *(const int4*)(Bp + (long long)gk0 * ldb + gn);
          else { for (int j = 0; j < 8; ++j) if (gn + j < N) r0[j] = Bp[(long long)gk0 * ldb + gn + j]; }
        }
        if (gk0 + 1 < Kvalid) {
          if (gn + 7 < N) *(int4*)r1 = *(const int4*)(Bp + (long long)(gk0 + 1) * ldb + gn);
          else { for (int j = 0; j < 8; ++j) if (gn + j < N) r1[j] = Bp[(long long)(gk0 + 1) * ldb + gn + j]; }
        }
#pragma unroll
        for (int j = 0; j < 8; ++j)
          *(unsigned int*)&Bs[(c8 + j) * LP + 2 * kp] =
              (unsigned int)r0[j] | ((unsigned int)r1[j] << 16);
      }
    }
    __syncthreads();

    // ---- fragments + MFMA ----
    short8 a[TM], b[TN];
#pragma unroll
    for (int m = 0; m < TM; ++m)
      a[m] = *(const short8*)&As[(wr * WM + m * 16 + lr) * LP + g * 8];
#pragma unroll
    for (int n = 0; n < TN; ++n)
      b[n] = *(const short8*)&Bs[(wc * WN + n * 16 + lr) * LP + g * 8];
#pragma unroll
    for (int m = 0; m < TM; ++m)
#pragma unroll
      for (int n = 0; n < TN; ++n)
        acc[m][n] = __builtin_amdgcn_mfma_f32_16x16x32_bf16(a[m], b[n], acc[m][n], 0, 0, 0);
    __syncthreads();
  }

  // ---- epilogue: D col = lane&15, row = (lane>>4)*4 + r ----
#pragma unroll
  for (int m = 0; m < TM; ++m) {
#pragma unroll
    for (int n = 0; n < TN; ++n) {
      const int gn = n0 + wc * WN + n * 16 + lr;
      if (gn >= N) continue;
      const float bv = bias ? bias[gn] : 0.f;
#pragma unroll
      for (int r = 0; r < 4; ++r) {
        const int gm = m0 + wr * WM + m * 16 + g * 4 + r;
        if (gm >= M) continue;
        const float v = acc[m][n][r] * alpha + bv;
        if constexpr (BF16C)
          ((unsigned short*)Cp)[coff + (long long)gm * ldc + gn] = f2bf(v);
        else
          ((float*)Cp)[coff + (long long)gm * ldc + gn] = v;
      }
    }
  }
}

// =================================================================
// fp32 vector-ALU GEMM (tiny patch-embed and head)
// =================================================================
template<int BM, int BN>
__global__ __launch_bounds__(256) void gemm_k(
    const float* __restrict__ A, long long sAz1, int lda,
    const float* __restrict__ B, int ldb,
    float* __restrict__ C, long long sCz1, int ldc,
    const float* __restrict__ bias,
    const float* __restrict__ resid, int ldr,
    float alpha, int M, int N, int K, int act)
{
  constexpr int BK = 16;
  constexpr int TM = BM / 16;
  constexpr int TN = BN / 16;
  __shared__ float As[BK][BM];
  __shared__ float Bs[BK][BN];

  const int z = blockIdx.z;
  A += z * sAz1;
  C += z * sCz1;
  const float* R = resid;

  const int tid = threadIdx.x;
  const int tx = tid & 15, ty = tid >> 4;
  const int m0 = blockIdx.y * BM, n0 = blockIdx.x * BN;

  float acc[TM][TN];
#pragma unroll
  for (int i = 0; i < TM; ++i)
#pragma unroll
    for (int j = 0; j < TN; ++j) acc[i][j] = 0.f;

  for (int k0 = 0; k0 < K; k0 += BK) {
    {
      constexpr int AV = (BM * BK / 4) / 256;
#pragma unroll
      for (int u = 0; u < AV; ++u) {
        const int vi = tid + u * 256;
        const int r  = vi / (BK / 4);
        const int c4 = (vi % (BK / 4)) * 4;
        const int gm = m0 + r, gk = k0 + c4;
        float4 v = {0.f, 0.f, 0.f, 0.f};
        if (gm < M) v = *(const float4*)(A + (long long)gm * lda + gk);
        As[c4 + 0][r] = v.x; As[c4 + 1][r] = v.y;
        As[c4 + 2][r] = v.z; As[c4 + 3][r] = v.w;
      }
    }
    {
      constexpr int BV = (BN * BK / 4) / 256;
#pragma unroll
      for (int u = 0; u < BV; ++u) {
        const int vi = tid + u * 256;
        const int r  = vi / (BK / 4);
        const int c4 = (vi % (BK / 4)) * 4;
        const int gn = n0 + r, gk = k0 + c4;
        float4 v = {0.f, 0.f, 0.f, 0.f};
        if (gn < N) v = *(const float4*)(B + (long long)gn * ldb + gk);
        Bs[c4 + 0][r] = v.x; Bs[c4 + 1][r] = v.y;
        Bs[c4 + 2][r] = v.z; Bs[c4 + 3][r] = v.w;
      }
    }
    __syncthreads();
#pragma unroll
    for (int kk = 0; kk < BK; ++kk) {
      float a[TM], bb[TN];
#pragma unroll
      for (int i = 0; i < TM; i += 4)
        *reinterpret_cast<float4*>(&a[i]) = *reinterpret_cast<const float4*>(&As[kk][ty * TM + i]);
#pragma unroll
      for (int j = 0; j < TN; j += 4)
        *reinterpret_cast<float4*>(&bb[j]) = *reinterpret_cast<const float4*>(&Bs[kk][tx * TN + j]);
#pragma unroll
      for (int i = 0; i < TM; ++i)
#pragma unroll
        for (int j = 0; j < TN; ++j) acc[i][j] = fmaf(a[i], bb[j], acc[i][j]);
    }
    __syncthreads();
  }

#pragma unroll
  for (int i = 0; i < TM; ++i) {
    const int gm = m0 + ty * TM + i;
    if (gm >= M) continue;
#pragma unroll
    for (int j = 0; j < TN; ++j) {
      const int gn = n0 + tx * TN + j;
      if (gn >= N) continue;
      float v = acc[i][j] * alpha;
      if (bias) v += bias[gn];
      if (R)    v += R[(long long)gm * ldr + gn];
      if (act)  v = tanhf(v);
      C[(long long)gm * ldc + gn] = v;
    }
  }
}

// ---------- LayerNorm over whole (SEQ,HID) per sample ----------
__global__ __launch_bounds__(256) void ln_part(const float* __restrict__ x, float* __restrict__ part) {
  const int b = blockIdx.x;            // 0..127
  const int n = b >> 4, seg = b & 15;
  const int per = (SEQL * HIDD / 4) / 16;
  const float4* px = (const float4*)(x + (size_t)n * SEQL * HIDD);
  float s = 0.f, q = 0.f;
  for (int i = seg * per + threadIdx.x; i < (seg + 1) * per; i += 256) {
    float4 v = px[i];
    s += v.x + v.y + v.z + v.w;
    q += v.x * v.x + v.y * v.y + v.z * v.z + v.w * v.w;
  }
  for (int o = 32; o; o >>= 1) { s += __shfl_xor(s, o, 64); q += __shfl_xor(q, o, 64); }
  __shared__ float ls[8];
  const int wid = threadIdx.x >> 6, lane = threadIdx.x & 63;
  if (lane == 0) { ls[wid] = s; ls[4 + wid] = q; }
  __syncthreads();
  if (threadIdx.x == 0) {
    part[b] = ls[0] + ls[1] + ls[2] + ls[3];
    part[128 + b] = ls[4] + ls[5] + ls[6] + ls[7];
  }
}

__global__ void ln_fin(float* __restrict__ stats) {
  const int n = blockIdx.x; const int lane = threadIdx.x;  // 64 threads
  float s = (lane < 16) ? stats[n * 16 + lane] : 0.f;
  float q = (lane < 16) ? stats[128 + n * 16 + lane] : 0.f;
  for (int o = 8; o; o >>= 1) { s += __shfl_xor(s, o, 64); q += __shfl_xor(q, o, 64); }
  if (lane == 0) {
    const float inv = 1.f / (float)(SEQL * HIDD);
    const float m = s * inv;
    const float var = q * inv - m * m;
    stats[256 + 2 * n] = m;
    stats[257 + 2 * n] = rsqrtf(var + EPSV);
  }
}

// LN apply -> bf16 output
__global__ __launch_bounds__(256) void ln_apply_bf(const float* __restrict__ x,
    const float* __restrict__ g, const float* __restrict__ b,
    const float* __restrict__ st, unsigned short* __restrict__ y)
{
  const int tot = NBATCH * SEQL * HIDD / 4;
  for (int i = blockIdx.x * 256 + threadIdx.x; i < tot; i += gridDim.x * 256) {
    const int n  = i / (SEQL * HIDD / 4);
    const int se = i - n * (SEQL * HIDD / 4);
    const float m = st[2 * n], r = st[2 * n + 1];
    float4 xv = ((const float4*)x)[i];
    float4 gv = ((const float4*)g)[se];
    float4 bv = ((const float4*)b)[se];
    ushort4 o;
    o.x = f2bf((xv.x - m) * r * gv.x + bv.x);
    o.y = f2bf((xv.y - m) * r * gv.y + bv.y);
    o.z = f2bf((xv.z - m) * r * gv.z + bv.z);
    o.w = f2bf((xv.w - m) * r * gv.w + bv.w);
    ((ushort4*)y)[i] = o;
  }
}

// ---------- softmax fp32 in (ld 224) -> bf16 out (ld 256, zero-padded) ----------
__global__ __launch_bounds__(256) void softmax_bf(const float* __restrict__ S,
                                                  unsigned short* __restrict__ P, int nrows) {
  const int row = blockIdx.x * 4 + (threadIdx.x >> 6);
  const int lane = threadIdx.x & 63;
  if (row >= nrows) return;
  const float* p = S + (long long)row * SLD;
  float v[4];
  float mx = -1e30f;
#pragma unroll
  for (int j = 0; j < 4; ++j) {
    const int t = lane + 64 * j;
    v[j] = (t < SEQL) ? p[t] : -1e30f;
    mx = fmaxf(mx, v[j]);
  }
  for (int o = 32; o; o >>= 1) mx = fmaxf(mx, __shfl_xor(mx, o, 64));
  float sum = 0.f;
#pragma unroll
  for (int j = 0; j < 4; ++j) {
    const int t = lane + 64 * j;
    v[j] = (t < SEQL) ? __expf(v[j] - mx) : 0.f;
    sum += v[j];
  }
  for (int o = 32; o; o >>= 1) sum += __shfl_xor(sum, o, 64);
  const float inv = 1.f / sum;
  unsigned short* q = P + (long long)row * PLD;
#pragma unroll
  for (int j = 0; j < 4; ++j) {
    const int t = lane + 64 * j;
    q[t] = f2bf(v[j] * inv);   // pad cols (>=SEQL) get 0
  }
}

// ---------- Wo split-K reduce: Ares = sum_s Cpart[s] + bo + Z ----------
__global__ __launch_bounds__(256) void wo_reduce(const float4* __restrict__ Cp,
    const float4* __restrict__ Z4, const float4* __restrict__ bo4,
    float4* __restrict__ out4)
{
  const int tot = M_ALL * HIDD / 4;    // 302592
  for (int i = blockIdx.x * 256 + threadIdx.x; i < tot; i += gridDim.x * 256) {
    float4 a = Cp[i], b = Cp[tot + i], c = Cp[2 * tot + i], d = Cp[3 * tot + i];
    float4 z = Z4[i];
    float4 bb = bo4[i % (HIDD / 4)];
    float4 o;
    o.x = a.x + b.x + c.x + d.x + z.x + bb.x;
    o.y = a.y + b.y + c.y + d.y + z.y + bb.y;
    o.z = a.z + b.z + c.z + d.z + z.z + bb.z;
    o.w = a.w + b.w + c.w + d.w + z.w + bb.w;
    out4[i] = o;
  }
}

// ---------- CLS row init ----------
__global__ void cls_pos(const float* __restrict__ cls, const float* __restrict__ pos,
                        float* __restrict__ Z) {
  const int n = blockIdx.x;
  for (int e = threadIdx.x; e < HIDD; e += 256)
    Z[(size_t)n * SEQL * HIDD + e] = cls[e] + pos[e];
}

// ---------------------------------------------------------------
extern "C" void kernel_launch(void* const* d_in, const int* in_sizes, int n_in,
                              void* d_out, int out_size, void* d_ws, size_t ws_size,
                              hipStream_t stream)
{
  const float* X    = (const float*)d_in[0];
  const float* Wp   = (const float*)d_in[1];
  const float* bp   = (const float*)d_in[2];
  const float* cls  = (const float*)d_in[3];
  const float* pos  = (const float*)d_in[4];
  const float* ln1g = (const float*)d_in[5];
  const float* ln1b = (const float*)d_in[6];
  const float* Wq   = (const float*)d_in[7];
  const float* bq   = (const float*)d_in[8];
  const float* Wk   = (const float*)d_in[9];
  const float* bk   = (const float*)d_in[10];
  const float* Wv   = (const float*)d_in[11];
  const float* bv   = (const float*)d_in[12];
  const float* Wo   = (const float*)d_in[13];
  const float* bo   = (const float*)d_in[14];
  const float* ln2g = (const float*)d_in[15];
  const float* ln2b = (const float*)d_in[16];
  const float* W2   = (const float*)d_in[17];
  const float* b2   = (const float*)d_in[18];
  const float* Wh   = (const float*)d_in[19];
  const float* bh   = (const float*)d_in[20];
  float* out = (float*)d_out;
  (void)in_sizes; (void)n_in; (void)out_size;

  char* base = (char*)d_ws;
  size_t off = 0;
  auto alloc = [&](size_t bytes) -> char* {
    char* r = base + off;
    off += (bytes + 255) & ~(size_t)255;
    return r;
  };
  const size_t ZB   = (size_t)M_ALL * HIDD * 4;              //  4.84 MB
  const size_t XB   = (size_t)M_ALL * HIDD * 2;              //  2.42 MB
  const size_t SFB  = (size_t)NBATCH * NHEADS * SEQL * SLD * 4;  // 16.95 MB
  const size_t PB   = (size_t)NBATCH * NHEADS * SEQL * PLD * 2;  //  9.69 MB
  const size_t QKVB = (size_t)M_ALL * HH3 * 2;               // 87.15 MB
  const size_t WQB  = (size_t)HH3 * HIDD * 2;                // 42.47 MB
  const size_t WOB  = (size_t)HH * HIDD * 2;                 // 14.16 MB
  const size_t W2B  = (size_t)HIDD * HIDD * 2;               //  1.18 MB

  float*          Z     = (float*)alloc(ZB);
  float*          Ares  = (float*)alloc(ZB);
  unsigned short* Xnb   = (unsigned short*)alloc(XB);
  float*          stats = (float*)alloc(4096);
  float*          Sf    = (float*)alloc(SFB);
  unsigned short* Pb    = (unsigned short*)alloc(PB);
  unsigned short* QKVb  = (unsigned short*)alloc(QKVB);   // Q|K|V col slices; H overwrites Q slice
  float*          Cpart = (float*)Sf;   // Wo split-K partials (19.4 MB <= Sf+Pb; both dead then)

  // big path: persistent bf16 weights (needs ~184 MB total ws)
  const bool big = ws_size >= (size_t)185 * 1024 * 1024;
  unsigned short *Wqkv_bf = nullptr, *Wo_bf = nullptr, *W2_bf = nullptr, *Wsc = nullptr;
  float* bqkv = nullptr;
  if (big) {
    Wqkv_bf = (unsigned short*)alloc(WQB);
    Wo_bf   = (unsigned short*)alloc(WOB);
    W2_bf   = (unsigned short*)alloc(W2B);
    bqkv    = (float*)alloc(HH3 * 4);
  } else {
    Wsc = (unsigned short*)alloc(WOB);   // rotating weight scratch (14.16 MB)
  }

  const float scale = 1.0f / ((float)HIDD * (float)HIDD);
  const long long sTn = (long long)SEQL * HH3;   // per-n row stride into QKVb
  const long long sSn = (long long)NHEADS * SEQL * SLD;
  const long long sSh = (long long)SEQL * SLD;
  const long long sPn = (long long)NHEADS * SEQL * PLD;
  const long long sPh = (long long)SEQL * PLD;
  const int WQKV4 = HH3 * HIDD / 4, WO4 = HH * HIDD / 4, W24 = HIDD * HIDD / 4;

  // ---- one-time weight conversion ----
  if (big) {
    cvt_bf<<<dim3(4096), 256, 0, stream>>>((const float4*)Wq, (ushort4*)(Wqkv_bf), WO4);
    cvt_bf<<<dim3(4096), 256, 0, stream>>>((const float4*)Wk, (ushort4*)(Wqkv_bf + (size_t)HH * HIDD), WO4);
    cvt_bf<<<dim3(4096), 256, 0, stream>>>((const float4*)Wv, (ushort4*)(Wqkv_bf + (size_t)2 * HH * HIDD), WO4);
    cvt_bf<<<dim3(4096), 256, 0, stream>>>((const float4*)Wo, (ushort4*)Wo_bf, WO4);
    cvt_bf<<<dim3(512),  256, 0, stream>>>((const float4*)W2, (ushort4*)W2_bf, W24);
    hipMemcpyAsync(bqkv,          bq, (size_t)HH * 4, hipMemcpyDeviceToDevice, stream);
    hipMemcpyAsync(bqkv + HH,     bk, (size_t)HH * 4, hipMemcpyDeviceToDevice, stream);
    hipMemcpyAsync(bqkv + 2 * HH, bv, (size_t)HH * 4, hipMemcpyDeviceToDevice, stream);
  }

  // ---- embed ----
  cls_pos<<<dim3(NBATCH), 256, 0, stream>>>(cls, pos, Z);
  gemm_k<64, 64><<<dim3(HIDD / 64, (NPATCH + 63) / 64, NBATCH), 256, 0, stream>>>(
      X, (long long)NPATCH * PATCHD, PATCHD,
      Wp, PATCHD,
      Z + HIDD, (long long)SEQL * HIDD, HIDD,
      bp, pos + HIDD, HIDD,
      1.0f, NPATCH, HIDD, PATCHD, 0);

  for (int blk = 0; blk < NBLOCKS; ++blk) {
    // ---- LN1 -> Xnb (bf16) ----
    ln_part<<<dim3(128), 256, 0, stream>>>(Z, stats);
    ln_fin<<<dim3(NBATCH), 64, 0, stream>>>(stats);
    ln_apply_bf<<<dim3(1182), 256, 0, stream>>>(Z, ln1g, ln1b, stats + 256, Xnb);

    // ---- QKV projections -> QKVb [1576, 27648] bf16 ----
    if (big) {
      gemm_mfma<128, 128, true, true><<<dim3(HH3 / 128, 13, 1), 256, 0, stream>>>(
          Xnb, 0, 0, HIDD, Wqkv_bf, 0, 0, HIDD, QKVb, 0, 0, HH3,
          bqkv, 1, 1.0f, M_ALL, HH3, HIDD, HIDD);
    } else {
      const float* Wf[3] = {Wq, Wk, Wv};
      const float* bf_[3] = {bq, bk, bv};
      for (int t = 0; t < 3; ++t) {
        cvt_bf<<<dim3(4096), 256, 0, stream>>>((const float4*)Wf[t], (ushort4*)Wsc, WO4);
        gemm_mfma<128, 128, true, true><<<dim3(HH / 128, 13, 1), 256, 0, stream>>>(
            Xnb, 0, 0, HIDD, Wsc, 0, 0, HIDD, QKVb + (size_t)t * HH, 0, 0, HH3,
            bf_[t], 1, 1.0f, M_ALL, HH, HIDD, HIDD);
      }
    }

    // ---- scores: Sf[z] = scale * Q[z] @ K[z]^T  (z = n*12+h) ----
    gemm_mfma<64, 64, true, false><<<dim3(4, 4, NBATCH * NHEADS), 256, 0, stream>>>(
        QKVb, sTn, HIDD, HH3,
        QKVb + HH, sTn, HIDD, HH3,
        Sf, sSn, sSh, SLD,
        nullptr, NHEADS, scale, SEQL, SEQL, HIDD, HIDD);

    // ---- softmax rows -> Pb ----
    softmax_bf<<<dim3(NBATCH * NHEADS * SEQL / 4), 256, 0, stream>>>(
        Sf, Pb, NBATCH * NHEADS * SEQL);

    // ---- PV: H[z] = P[z] @ V[z]; H written into the (dead) Q column slice ----
    gemm_mfma<64, 128, false, true><<<dim3(HIDD / 128, 4, NBATCH * NHEADS), 256, 0, stream>>>(
        Pb, sPn, sPh, PLD,
        QKVb + 2 * HH, sTn, HIDD, HH3,
        QKVb, sTn, HIDD, HH3,
        nullptr, NHEADS, 1.0f, SEQL, HIDD, KPV, SEQL);

    // ---- Wo split-K: Cpart[s] = H[:, s*2304:(s+1)*2304] @ Wo_s^T ----
    if (!big)
      cvt_bf<<<dim3(4096), 256, 0, stream>>>((const float4*)Wo, (ushort4*)Wsc, WO4);
    gemm_mfma<128, 128, true, false><<<dim3(HIDD / 128, 13, KSPLIT), 256, 0, stream>>>(
        QKVb, 0, HH / KSPLIT, HH3,
        big ? Wo_bf : Wsc, 0, HH / KSPLIT, HH,
        Cpart, 0, (long long)M_ALL * HIDD, HIDD,
        nullptr, KSPLIT, 1.0f, M_ALL, HIDD, HH / KSPLIT, HH / KSPLIT);

    // ---- reduce + bias + residual -> Ares ----
    wo_reduce<<<dim3(1182), 256, 0, stream>>>(
        (const float4*)Cpart, (const float4*)Z, (const float4*)bo, (float4*)Ares);

    // ---- LN2 -> Xnb (bf16) ----
    ln_part<<<dim3(128), 256, 0, stream>>>(Ares, stats);
    ln_fin<<<dim3(NBATCH), 64, 0, stream>>>(stats);
    ln_apply_bf<<<dim3(1182), 256, 0, stream>>>(Ares, ln2g, ln2b, stats + 256, Xnb);

    // ---- W2: Z = Xnb @ W2^T + b2 (fp32 out) ----
    if (!big)
      cvt_bf<<<dim3(512), 256, 0, stream>>>((const float4*)W2, (ushort4*)Wsc, W24);
    gemm_mfma<128, 64, true, false><<<dim3(HIDD / 64, 13, 1), 256, 0, stream>>>(
        Xnb, 0, 0, HIDD, big ? W2_bf : Wsc, 0, 0, HIDD, Z, 0, 0, HIDD,
        b2, 1, 1.0f, M_ALL, HIDD, HIDD, HIDD);
  }

  // ---- head: out = tanh(Z[:,0,:] @ Wh^T + bh) ----
  gemm_k<64, 64><<<dim3((OUTDIM + 63) / 64, 1, 1), 256, 0, stream>>>(
      Z, 0, SEQL * HIDD,
      Wh, HIDD,
      out, 0, OUTDIM,
      bh, nullptr, 0,
      1.0f, NBATCH, OUTDIM, HIDD, 1);
}

// Round 5
// 2075.516 us; speedup vs baseline: 5.5462x; 1.2678x over previous
//
#include <hip/hip_runtime.h>
#include <hip/hip_bf16.h>
#include <math.h>

typedef __hip_bfloat16 bf16;
typedef __attribute__((ext_vector_type(8))) short short8;
typedef __attribute__((ext_vector_type(4))) float f32x4;

#define HIDD   768
#define SEQL   197
#define NPATCH 196
#define PATCHD 256
#define NHEADS 12
#define NBATCH 8
#define OUTDIM 1000
#define NBLOCKS 6
#define EPSV   1e-5f
#define HH     (NHEADS * HIDD)       /* 9216 */
#define HH3    (3 * HH)              /* 27648 */
#define M_ALL  (NBATCH * SEQL)       /* 1576 */
#define SLD    224                   /* fp32 score row stride */
#define PLD    256                   /* bf16 prob row stride (zero-padded cols) */
#define KPV    224                   /* PV reduction length: 197 -> ceil32 */
#define KSPLIT 4

// ---------- helpers ----------
__device__ __forceinline__ unsigned short f2bf(float f) {
  union { bf16 h; unsigned short u; } cv; cv.h = __float2bfloat16(f); return cv.u;
}

typedef __attribute__((address_space(3))) unsigned int lds_uint;
typedef __attribute__((address_space(1))) const unsigned int g_uint;
__device__ __forceinline__ void gload16(const void* g, void* l) {
  // async global->LDS, 16 B per lane; LDS dest = wave-uniform base + lane*16
  __builtin_amdgcn_global_load_lds((g_uint*)g, (lds_uint*)l, 16, 0, 0);
}

// ---------- fp32 -> bf16 convert ----------
__global__ __launch_bounds__(256) void cvt_bf(const float4* __restrict__ src,
                                              ushort4* __restrict__ dst, int n4) {
  for (int i = blockIdx.x * 256 + threadIdx.x; i < n4; i += gridDim.x * 256) {
    float4 v = src[i];
    ushort4 o;
    o.x = f2bf(v.x); o.y = f2bf(v.y); o.z = f2bf(v.z); o.w = f2bf(v.w);
    dst[i] = o;
  }
}

// =================================================================
// gemm_bt: C = alpha * A @ B^T + bias.  A [M,K] bf16 (lda), B [N,K] bf16 (ldb).
// m97 structure: global_load_lds width-16 staging, double-buffered linear LDS,
// one __syncthreads per K-step (its vmcnt drain lands after the MFMAs).
// K % 32 == 0. M/N edge tiles: global reads run past M rows (caller guarantees
// the overflow addresses stay inside the workspace); stores are masked.
// =================================================================
template<int BM, int BN, bool BF16C>
__global__ __launch_bounds__(256) void gemm_bt(
    const unsigned short* __restrict__ A, long long sAz1, long long sAz2, int lda,
    const unsigned short* __restrict__ B, long long sBz1, long long sBz2, int ldb,
    void* __restrict__ Cp, long long sCz1, long long sCz2, int ldc,
    const float* __restrict__ bias, int zdiv, float alpha,
    int M, int N, int K)
{
  constexpr int BK = 32;
  __shared__ unsigned short As[2][BM * BK];
  __shared__ unsigned short Bs[2][BN * BK];

  const int z  = blockIdx.z;
  const int z1 = z / zdiv, z2 = z - z1 * zdiv;
  const unsigned short* Ab = A + z1 * sAz1 + z2 * sAz2;
  const unsigned short* Bb = B + z1 * sBz1 + z2 * sBz2;
  const long long coff = z1 * sCz1 + z2 * sCz2;

  const int tid = threadIdx.x;
  const int m0 = blockIdx.y * BM, n0 = blockIdx.x * BN;
  const int lane = tid & 63, wid = tid >> 6;
  const int wr = wid >> 1, wc = wid & 1;
  constexpr int WM = BM / 2, WN = BN / 2, TM = WM / 16, TN = WN / 16;
  const int lr = lane & 15, g = lane >> 4;

  // staging geometry: per issue a wave covers 16 rows (4 lanes/row, 16 B each)
  const int sr = wid * 16 + (lane >> 2);     // row within the 64-row issue group
  const int sc = (lane & 3) * 8;             // bf16 column offset (16 B chunk)
  const int wbyte = wid * 1024;              // wave's LDS byte base within an issue

  f32x4 acc[TM][TN];
#pragma unroll
  for (int m = 0; m < TM; ++m)
#pragma unroll
    for (int n = 0; n < TN; ++n) acc[m][n] = (f32x4){0.f, 0.f, 0.f, 0.f};

  auto stage = [&](int bufi, int kt) {
    const int k0 = kt * BK;
#pragma unroll
    for (int u = 0; u < BM / 64; ++u)
      gload16(Ab + (long long)(m0 + u * 64 + sr) * lda + k0 + sc,
              (char*)&As[bufi][0] + u * 4096 + wbyte);
#pragma unroll
    for (int u = 0; u < BN / 64; ++u)
      gload16(Bb + (long long)(n0 + u * 64 + sr) * ldb + k0 + sc,
              (char*)&Bs[bufi][0] + u * 4096 + wbyte);
  };

  const int ktiles = K / BK;
  stage(0, 0);
  __syncthreads();
  int cur = 0;
  for (int t = 0; t < ktiles; ++t) {
    if (t + 1 < ktiles) stage(cur ^ 1, t + 1);   // prefetch overlaps ds_read+MFMA
    short8 a[TM], b[TN];
#pragma unroll
    for (int m = 0; m < TM; ++m)
      a[m] = *(const short8*)&As[cur][(wr * WM + m * 16 + lr) * BK + g * 8];
#pragma unroll
    for (int n = 0; n < TN; ++n)
      b[n] = *(const short8*)&Bs[cur][(wc * WN + n * 16 + lr) * BK + g * 8];
#pragma unroll
    for (int m = 0; m < TM; ++m)
#pragma unroll
      for (int n = 0; n < TN; ++n)
        acc[m][n] = __builtin_amdgcn_mfma_f32_16x16x32_bf16(a[m], b[n], acc[m][n], 0, 0, 0);
    __syncthreads();   // drains vmcnt(0) (prefetch) + lgkmcnt, then barrier
    cur ^= 1;
  }

  // ---- epilogue: D col = lane&15, row = (lane>>4)*4 + r ----
#pragma unroll
  for (int m = 0; m < TM; ++m) {
#pragma unroll
    for (int n = 0; n < TN; ++n) {
      const int gn = n0 + wc * WN + n * 16 + lr;
      if (gn >= N) continue;
      const float bv = bias ? bias[gn] : 0.f;
#pragma unroll
      for (int r = 0; r < 4; ++r) {
        const int gm = m0 + wr * WM + m * 16 + g * 4 + r;
        if (gm >= M) continue;
        const float v = acc[m][n][r] * alpha + bv;
        if constexpr (BF16C)
          ((unsigned short*)Cp)[coff + (long long)gm * ldc + gn] = f2bf(v);
        else
          ((float*)Cp)[coff + (long long)gm * ldc + gn] = v;
      }
    }
  }
}

// =================================================================
// Old reg-staged MFMA GEMM, kept for PV only (BT=false transpose staging).
// C = alpha * A @ B + bias; B is [K,N] (rows k >= Kvalid staged as zero).
// =================================================================
template<int BM, int BN, bool BF16C>
__global__ __launch_bounds__(256) void gemm_nn(
    const unsigned short* __restrict__ A, long long sAz1, long long sAz2, int lda,
    const unsigned short* __restrict__ Bb, long long sBz1, long long sBz2, int ldb,
    void* __restrict__ Cp, long long sCz1, long long sCz2, int ldc,
    const float* __restrict__ bias, int zdiv, float alpha,
    int M, int N, int K, int Kvalid)
{
  constexpr int BK = 32;
  constexpr int LP = 40;
  __shared__ unsigned short As[BM * LP];
  __shared__ unsigned short Bs[BN * LP];

  const int z  = blockIdx.z;
  const int z1 = z / zdiv, z2 = z - z1 * zdiv;
  const unsigned short* Ab = A + z1 * sAz1 + z2 * sAz2;
  const unsigned short* Bp = Bb + z1 * sBz1 + z2 * sBz2;
  const long long coff = z1 * sCz1 + z2 * sCz2;

  const int tid = threadIdx.x;
  const int m0 = blockIdx.y * BM, n0 = blockIdx.x * BN;
  const int lane = tid & 63, wid = tid >> 6;
  const int wr = wid >> 1, wc = wid & 1;
  constexpr int WM = BM / 2, WN = BN / 2, TM = WM / 16, TN = WN / 16;
  const int lr = lane & 15, g = lane >> 4;
  const int srow = tid >> 2, scg = tid & 3;

  f32x4 acc[TM][TN];
#pragma unroll
  for (int m = 0; m < TM; ++m)
#pragma unroll
    for (int n = 0; n < TN; ++n) acc[m][n] = (f32x4){0.f, 0.f, 0.f, 0.f};

  for (int k0 = 0; k0 < K; k0 += BK) {
#pragma unroll
    for (int u = 0; u < BM / 64; ++u) {
      const int row = u * 64 + srow;
      const int gm = m0 + row;
      int4 val = {0, 0, 0, 0};
      if (gm < M)
        val = *(const int4*)(Ab + (long long)gm * lda + k0 + scg * 8);
      *(int4*)&As[row * LP + scg * 8] = val;
    }
    {
      constexpr int CH = BN / 8;
      constexpr int KP = BK / 2;
      static_assert(KP * CH <= 256, "staging exceeds block");
      if (tid < KP * CH) {
        const int kp = tid / CH;
        const int c8 = (tid - kp * CH) * 8;
        const int gn = n0 + c8;
        const int gk0 = k0 + 2 * kp;
        unsigned short r0[8] = {0,0,0,0,0,0,0,0};
        unsigned short r1[8] = {0,0,0,0,0,0,0,0};
        if (gk0 < Kvalid) {
          if (gn + 7 < N) *(int4*)r0 = *(const int4*)(Bp + (long long)gk0 * ldb + gn);
          else { for (int j = 0; j < 8; ++j) if (gn + j < N) r0[j] = Bp[(long long)gk0 * ldb + gn + j]; }
        }
        if (gk0 + 1 < Kvalid) {
          if (gn + 7 < N) *(int4*)r1 = *(const int4*)(Bp + (long long)(gk0 + 1) * ldb + gn);
          else { for (int j = 0; j < 8; ++j) if (gn + j < N) r1[j] = Bp[(long long)(gk0 + 1) * ldb + gn + j]; }
        }
#pragma unroll
        for (int j = 0; j < 8; ++j)
          *(unsigned int*)&Bs[(c8 + j) * LP + 2 * kp] =
              (unsigned int)r0[j] | ((unsigned int)r1[j] << 16);
      }
    }
    __syncthreads();

    short8 a[TM], b[TN];
#pragma unroll
    for (int m = 0; m < TM; ++m)
      a[m] = *(const short8*)&As[(wr * WM + m * 16 + lr) * LP + g * 8];
#pragma unroll
    for (int n = 0; n < TN; ++n)
      b[n] = *(const short8*)&Bs[(wc * WN + n * 16 + lr) * LP + g * 8];
#pragma unroll
    for (int m = 0; m < TM; ++m)
#pragma unroll
      for (int n = 0; n < TN; ++n)
        acc[m][n] = __builtin_amdgcn_mfma_f32_16x16x32_bf16(a[m], b[n], acc[m][n], 0, 0, 0);
    __syncthreads();
  }

#pragma unroll
  for (int m = 0; m < TM; ++m) {
#pragma unroll
    for (int n = 0; n < TN; ++n) {
      const int gn = n0 + wc * WN + n * 16 + lr;
      if (gn >= N) continue;
      const float bv = bias ? bias[gn] : 0.f;
#pragma unroll
      for (int r = 0; r < 4; ++r) {
        const int gm = m0 + wr * WM + m * 16 + g * 4 + r;
        if (gm >= M) continue;
        const float v = acc[m][n][r] * alpha + bv;
        if constexpr (BF16C)
          ((unsigned short*)Cp)[coff + (long long)gm * ldc + gn] = f2bf(v);
        else
          ((float*)Cp)[coff + (long long)gm * ldc + gn] = v;
      }
    }
  }
}

// =================================================================
// fp32 vector-ALU GEMM (tiny patch-embed and head)
// =================================================================
template<int BM, int BN>
__global__ __launch_bounds__(256) void gemm_k(
    const float* __restrict__ A, long long sAz1, int lda,
    const float* __restrict__ B, int ldb,
    float* __restrict__ C, long long sCz1, int ldc,
    const float* __restrict__ bias,
    const float* __restrict__ resid, int ldr,
    float alpha, int M, int N, int K, int act)
{
  constexpr int BK = 16;
  constexpr int TM = BM / 16;
  constexpr int TN = BN / 16;
  __shared__ float As[BK][BM];
  __shared__ float Bs[BK][BN];

  const int z = blockIdx.z;
  A += z * sAz1;
  C += z * sCz1;
  const float* R = resid;

  const int tid = threadIdx.x;
  const int tx = tid & 15, ty = tid >> 4;
  const int m0 = blockIdx.y * BM, n0 = blockIdx.x * BN;

  float acc[TM][TN];
#pragma unroll
  for (int i = 0; i < TM; ++i)
#pragma unroll
    for (int j = 0; j < TN; ++j) acc[i][j] = 0.f;

  for (int k0 = 0; k0 < K; k0 += BK) {
    {
      constexpr int AV = (BM * BK / 4) / 256;
#pragma unroll
      for (int u = 0; u < AV; ++u) {
        const int vi = tid + u * 256;
        const int r  = vi / (BK / 4);
        const int c4 = (vi % (BK / 4)) * 4;
        const int gm = m0 + r, gk = k0 + c4;
        float4 v = {0.f, 0.f, 0.f, 0.f};
        if (gm < M) v = *(const float4*)(A + (long long)gm * lda + gk);
        As[c4 + 0][r] = v.x; As[c4 + 1][r] = v.y;
        As[c4 + 2][r] = v.z; As[c4 + 3][r] = v.w;
      }
    }
    {
      constexpr int BV = (BN * BK / 4) / 256;
#pragma unroll
      for (int u = 0; u < BV; ++u) {
        const int vi = tid + u * 256;
        const int r  = vi / (BK / 4);
        const int c4 = (vi % (BK / 4)) * 4;
        const int gn = n0 + r, gk = k0 + c4;
        float4 v = {0.f, 0.f, 0.f, 0.f};
        if (gn < N) v = *(const float4*)(B + (long long)gn * ldb + gk);
        Bs[c4 + 0][r] = v.x; Bs[c4 + 1][r] = v.y;
        Bs[c4 + 2][r] = v.z; Bs[c4 + 3][r] = v.w;
      }
    }
    __syncthreads();
#pragma unroll
    for (int kk = 0; kk < BK; ++kk) {
      float a[TM], bb[TN];
#pragma unroll
      for (int i = 0; i < TM; i += 4)
        *reinterpret_cast<float4*>(&a[i]) = *reinterpret_cast<const float4*>(&As[kk][ty * TM + i]);
#pragma unroll
      for (int j = 0; j < TN; j += 4)
        *reinterpret_cast<float4*>(&bb[j]) = *reinterpret_cast<const float4*>(&Bs[kk][tx * TN + j]);
#pragma unroll
      for (int i = 0; i < TM; ++i)
#pragma unroll
        for (int j = 0; j < TN; ++j) acc[i][j] = fmaf(a[i], bb[j], acc[i][j]);
    }
    __syncthreads();
  }

#pragma unroll
  for (int i = 0; i < TM; ++i) {
    const int gm = m0 + ty * TM + i;
    if (gm >= M) continue;
#pragma unroll
    for (int j = 0; j < TN; ++j) {
      const int gn = n0 + tx * TN + j;
      if (gn >= N) continue;
      float v = acc[i][j] * alpha;
      if (bias) v += bias[gn];
      if (R)    v += R[(long long)gm * ldr + gn];
      if (act)  v = tanhf(v);
      C[(long long)gm * ldc + gn] = v;
    }
  }
}

// ---------- LayerNorm over whole (SEQ,HID) per sample ----------
__global__ __launch_bounds__(256) void ln_part(const float* __restrict__ x, float* __restrict__ part) {
  const int b = blockIdx.x;            // 0..127
  const int n = b >> 4, seg = b & 15;
  const int per = (SEQL * HIDD / 4) / 16;
  const float4* px = (const float4*)(x + (size_t)n * SEQL * HIDD);
  float s = 0.f, q = 0.f;
  for (int i = seg * per + threadIdx.x; i < (seg + 1) * per; i += 256) {
    float4 v = px[i];
    s += v.x + v.y + v.z + v.w;
    q += v.x * v.x + v.y * v.y + v.z * v.z + v.w * v.w;
  }
  for (int o = 32; o; o >>= 1) { s += __shfl_xor(s, o, 64); q += __shfl_xor(q, o, 64); }
  __shared__ float ls[8];
  const int wid = threadIdx.x >> 6, lane = threadIdx.x & 63;
  if (lane == 0) { ls[wid] = s; ls[4 + wid] = q; }
  __syncthreads();
  if (threadIdx.x == 0) {
    part[b] = ls[0] + ls[1] + ls[2] + ls[3];
    part[128 + b] = ls[4] + ls[5] + ls[6] + ls[7];
  }
}

__global__ void ln_fin(float* __restrict__ stats) {
  const int n = blockIdx.x; const int lane = threadIdx.x;  // 64 threads
  float s = (lane < 16) ? stats[n * 16 + lane] : 0.f;
  float q = (lane < 16) ? stats[128 + n * 16 + lane] : 0.f;
  for (int o = 8; o; o >>= 1) { s += __shfl_xor(s, o, 64); q += __shfl_xor(q, o, 64); }
  if (lane == 0) {
    const float inv = 1.f / (float)(SEQL * HIDD);
    const float m = s * inv;
    const float var = q * inv - m * m;
    stats[256 + 2 * n] = m;
    stats[257 + 2 * n] = rsqrtf(var + EPSV);
  }
}

// LN apply -> bf16
__global__ __launch_bounds__(256) void ln_apply_bf(const float* __restrict__ x,
    const float* __restrict__ g, const float* __restrict__ b,
    const float* __restrict__ st, unsigned short* __restrict__ y)
{
  const int tot = NBATCH * SEQL * HIDD / 4;
  for (int i = blockIdx.x * 256 + threadIdx.x; i < tot; i += gridDim.x * 256) {
    const int n  = i / (SEQL * HIDD / 4);
    const int se = i - n * (SEQL * HIDD / 4);
    const float m = st[2 * n], r = st[2 * n + 1];
    float4 xv = ((const float4*)x)[i];
    float4 gv = ((const float4*)g)[se];
    float4 bv = ((const float4*)b)[se];
    ushort4 o;
    o.x = f2bf((xv.x - m) * r * gv.x + bv.x);
    o.y = f2bf((xv.y - m) * r * gv.y + bv.y);
    o.z = f2bf((xv.z - m) * r * gv.z + bv.z);
    o.w = f2bf((xv.w - m) * r * gv.w + bv.w);
    ((ushort4*)y)[i] = o;
  }
}

// ---------- softmax fp32 (ld 224) -> bf16 (ld 256, zero-padded) ----------
__global__ __launch_bounds__(256) void softmax_bf(const float* __restrict__ S,
                                                  unsigned short* __restrict__ P, int nrows) {
  const int row = blockIdx.x * 4 + (threadIdx.x >> 6);
  const int lane = threadIdx.x & 63;
  if (row >= nrows) return;
  const float* p = S + (long long)row * SLD;
  float v[4];
  float mx = -1e30f;
#pragma unroll
  for (int j = 0; j < 4; ++j) {
    const int t = lane + 64 * j;
    v[j] = (t < SEQL) ? p[t] : -1e30f;
    mx = fmaxf(mx, v[j]);
  }
  for (int o = 32; o; o >>= 1) mx = fmaxf(mx, __shfl_xor(mx, o, 64));
  float sum = 0.f;
#pragma unroll
  for (int j = 0; j < 4; ++j) {
    const int t = lane + 64 * j;
    v[j] = (t < SEQL) ? __expf(v[j] - mx) : 0.f;
    sum += v[j];
  }
  for (int o = 32; o; o >>= 1) sum += __shfl_xor(sum, o, 64);
  const float inv = 1.f / sum;
  unsigned short* q = P + (long long)row * PLD;
#pragma unroll
  for (int j = 0; j < 4; ++j) {
    const int t = lane + 64 * j;
    q[t] = f2bf(v[j] * inv);
  }
}

// ---------- Wo split-K reduce: Ares = sum_s Cpart[s] + bo + Z ----------
__global__ __launch_bounds__(256) void wo_reduce(const float4* __restrict__ Cp,
    const float4* __restrict__ Z4, const float4* __restrict__ bo4,
    float4* __restrict__ out4)
{
  const int tot = M_ALL * HIDD / 4;
  for (int i = blockIdx.x * 256 + threadIdx.x; i < tot; i += gridDim.x * 256) {
    float4 a = Cp[i], b = Cp[tot + i], c = Cp[2 * tot + i], d = Cp[3 * tot + i];
    float4 z = Z4[i];
    float4 bb = bo4[i % (HIDD / 4)];
    float4 o;
    o.x = a.x + b.x + c.x + d.x + z.x + bb.x;
    o.y = a.y + b.y + c.y + d.y + z.y + bb.y;
    o.z = a.z + b.z + c.z + d.z + z.z + bb.z;
    o.w = a.w + b.w + c.w + d.w + z.w + bb.w;
    out4[i] = o;
  }
}

// ---------- CLS row init ----------
__global__ void cls_pos(const float* __restrict__ cls, const float* __restrict__ pos,
                        float* __restrict__ Z) {
  const int n = blockIdx.x;
  for (int e = threadIdx.x; e < HIDD; e += 256)
    Z[(size_t)n * SEQL * HIDD + e] = cls[e] + pos[e];
}

// ---------------------------------------------------------------
extern "C" void kernel_launch(void* const* d_in, const int* in_sizes, int n_in,
                              void* d_out, int out_size, void* d_ws, size_t ws_size,
                              hipStream_t stream)
{
  const float* X    = (const float*)d_in[0];
  const float* Wp   = (const float*)d_in[1];
  const float* bp   = (const float*)d_in[2];
  const float* cls  = (const float*)d_in[3];
  const float* pos  = (const float*)d_in[4];
  const float* ln1g = (const float*)d_in[5];
  const float* ln1b = (const float*)d_in[6];
  const float* Wq   = (const float*)d_in[7];
  const float* bq   = (const float*)d_in[8];
  const float* Wk   = (const float*)d_in[9];
  const float* bk   = (const float*)d_in[10];
  const float* Wv   = (const float*)d_in[11];
  const float* bv   = (const float*)d_in[12];
  const float* Wo   = (const float*)d_in[13];
  const float* bo   = (const float*)d_in[14];
  const float* ln2g = (const float*)d_in[15];
  const float* ln2b = (const float*)d_in[16];
  const float* W2   = (const float*)d_in[17];
  const float* b2   = (const float*)d_in[18];
  const float* Wh   = (const float*)d_in[19];
  const float* bh   = (const float*)d_in[20];
  float* out = (float*)d_out;
  (void)in_sizes; (void)n_in; (void)out_size; (void)ws_size;

  // NOTE: allocation ORDER matters — gemm_bt edge tiles read up to ~5 MB past
  // QKVb/Pb/Xnb ends; the weight copies placed after them keep those reads mapped.
  char* base = (char*)d_ws;
  size_t off = 0;
  auto alloc = [&](size_t bytes) -> char* {
    char* r = base + off;
    off += (bytes + 255) & ~(size_t)255;
    return r;
  };
  const size_t ZB   = (size_t)M_ALL * HIDD * 4;
  const size_t XB   = (size_t)M_ALL * HIDD * 2;
  const size_t SFB  = (size_t)NBATCH * NHEADS * SEQL * SLD * 4;
  const size_t PB   = (size_t)NBATCH * NHEADS * SEQL * PLD * 2;
  const size_t QKVB = (size_t)M_ALL * HH3 * 2;               // 87.15 MB
  const size_t WQB  = (size_t)HH3 * HIDD * 2;                // 42.47 MB
  const size_t WOB  = (size_t)HH * HIDD * 2;                 // 14.16 MB
  const size_t W2B  = (size_t)HIDD * HIDD * 2;

  float*          Z     = (float*)alloc(ZB);
  float*          Ares  = (float*)alloc(ZB);
  unsigned short* Xnb   = (unsigned short*)alloc(XB);
  float*          stats = (float*)alloc(4096);
  float*          Sf    = (float*)alloc(SFB);
  unsigned short* Pb    = (unsigned short*)alloc(PB);
  unsigned short* QKVb  = (unsigned short*)alloc(QKVB);   // Q|K|V slices; H overwrites Q
  unsigned short* Wqkv_bf = (unsigned short*)alloc(WQB);
  unsigned short* Wo_bf   = (unsigned short*)alloc(WOB);
  unsigned short* W2_bf   = (unsigned short*)alloc(W2B);
  float*          bqkv    = (float*)alloc(HH3 * 4);
  float*          Cpart   = (float*)Sf;   // Wo split-K partials alias Sf

  const float scale = 1.0f / ((float)HIDD * (float)HIDD);
  const long long sTn = (long long)SEQL * HH3;
  const long long sSn = (long long)NHEADS * SEQL * SLD;
  const long long sSh = (long long)SEQL * SLD;
  const long long sPn = (long long)NHEADS * SEQL * PLD;
  const long long sPh = (long long)SEQL * PLD;
  const int WO4 = HH * HIDD / 4, W24 = HIDD * HIDD / 4;

  // ---- one-time weight conversion ----
  cvt_bf<<<dim3(4096), 256, 0, stream>>>((const float4*)Wq, (ushort4*)(Wqkv_bf), WO4);
  cvt_bf<<<dim3(4096), 256, 0, stream>>>((const float4*)Wk, (ushort4*)(Wqkv_bf + (size_t)HH * HIDD), WO4);
  cvt_bf<<<dim3(4096), 256, 0, stream>>>((const float4*)Wv, (ushort4*)(Wqkv_bf + (size_t)2 * HH * HIDD), WO4);
  cvt_bf<<<dim3(4096), 256, 0, stream>>>((const float4*)Wo, (ushort4*)Wo_bf, WO4);
  cvt_bf<<<dim3(512),  256, 0, stream>>>((const float4*)W2, (ushort4*)W2_bf, W24);
  hipMemcpyAsync(bqkv,          bq, (size_t)HH * 4, hipMemcpyDeviceToDevice, stream);
  hipMemcpyAsync(bqkv + HH,     bk, (size_t)HH * 4, hipMemcpyDeviceToDevice, stream);
  hipMemcpyAsync(bqkv + 2 * HH, bv, (size_t)HH * 4, hipMemcpyDeviceToDevice, stream);

  // ---- embed ----
  cls_pos<<<dim3(NBATCH), 256, 0, stream>>>(cls, pos, Z);
  gemm_k<64, 64><<<dim3(HIDD / 64, (NPATCH + 63) / 64, NBATCH), 256, 0, stream>>>(
      X, (long long)NPATCH * PATCHD, PATCHD,
      Wp, PATCHD,
      Z + HIDD, (long long)SEQL * HIDD, HIDD,
      bp, pos + HIDD, HIDD,
      1.0f, NPATCH, HIDD, PATCHD, 0);

  for (int blk = 0; blk < NBLOCKS; ++blk) {
    // ---- LN1 -> Xnb (bf16) ----
    ln_part<<<dim3(128), 256, 0, stream>>>(Z, stats);
    ln_fin<<<dim3(NBATCH), 64, 0, stream>>>(stats);
    ln_apply_bf<<<dim3(1182), 256, 0, stream>>>(Z, ln1g, ln1b, stats + 256, Xnb);

    // ---- fused QKV: [1576,768] @ [27648,768]^T -> bf16 [1576,27648] ----
    gemm_bt<128, 128, true><<<dim3(HH3 / 128, 13, 1), 256, 0, stream>>>(
        Xnb, 0, 0, HIDD, Wqkv_bf, 0, 0, HIDD, QKVb, 0, 0, HH3,
        bqkv, 1, 1.0f, M_ALL, HH3, HIDD);

    // ---- scores: Sf[z] = scale * Q[z] @ K[z]^T  (z = n*12+h) ----
    gemm_bt<64, 64, false><<<dim3(4, 4, NBATCH * NHEADS), 256, 0, stream>>>(
        QKVb, sTn, HIDD, HH3,
        QKVb + HH, sTn, HIDD, HH3,
        Sf, sSn, sSh, SLD,
        nullptr, NHEADS, scale, SEQL, SEQL, HIDD);

    // ---- softmax rows -> Pb ----
    softmax_bf<<<dim3(NBATCH * NHEADS * SEQL / 4), 256, 0, stream>>>(
        Sf, Pb, NBATCH * NHEADS * SEQL);

    // ---- PV: H[z] = P[z] @ V[z]; H into the dead Q column slice ----
    gemm_nn<64, 128, true><<<dim3(HIDD / 128, 4, NBATCH * NHEADS), 256, 0, stream>>>(
        Pb, sPn, sPh, PLD,
        QKVb + 2 * HH, sTn, HIDD, HH3,
        QKVb, sTn, HIDD, HH3,
        nullptr, NHEADS, 1.0f, SEQL, HIDD, KPV, SEQL);

    // ---- Wo split-K: Cpart[s] = H[:, s*2304:(s+1)*2304] @ Wo_s^T ----
    gemm_bt<128, 128, false><<<dim3(HIDD / 128, 13, KSPLIT), 256, 0, stream>>>(
        QKVb, 0, HH / KSPLIT, HH3,
        Wo_bf, 0, HH / KSPLIT, HH,
        Cpart, 0, (long long)M_ALL * HIDD, HIDD,
        nullptr, KSPLIT, 1.0f, M_ALL, HIDD, HH / KSPLIT);

    // ---- reduce + bias + residual -> Ares ----
    wo_reduce<<<dim3(1182), 256, 0, stream>>>(
        (const float4*)Cpart, (const float4*)Z, (const float4*)bo, (float4*)Ares);

    // ---- LN2 -> Xnb (bf16) ----
    ln_part<<<dim3(128), 256, 0, stream>>>(Ares, stats);
    ln_fin<<<dim3(NBATCH), 64, 0, stream>>>(stats);
    ln_apply_bf<<<dim3(1182), 256, 0, stream>>>(Ares, ln2g, ln2b, stats + 256, Xnb);

    // ---- W2: Z = Xnb @ W2^T + b2 (fp32 out) ----
    gemm_bt<128, 64, false><<<dim3(HIDD / 64, 13, 1), 256, 0, stream>>>(
        Xnb, 0, 0, HIDD, W2_bf, 0, 0, HIDD, Z, 0, 0, HIDD,
        b2, 1, 1.0f, M_ALL, HIDD, HIDD);
  }

  // ---- head: out = tanh(Z[:,0,:] @ Wh^T + bh) ----
  gemm_k<64, 64><<<dim3((OUTDIM + 63) / 64, 1, 1), 256, 0, stream>>>(
      Z, 0, SEQL * HIDD,
      Wh, HIDD,
      out, 0, OUTDIM,
      bh, nullptr, 0,
      1.0f, NBATCH, OUTDIM, HIDD, 1);
}